// Round 4
// baseline (234.377 us; speedup 1.0000x reference)
//
#include <hip/hip_runtime.h>
#include <stdint.h>

typedef __attribute__((ext_vector_type(8))) short short8v;
typedef __attribute__((ext_vector_type(4))) float f32x4;

#define MARG 0.0625f

// async global->LDS, 16B per lane
__device__ __forceinline__ void glds16(const void* g, void* l) {
  __builtin_amdgcn_global_load_lds(
      (const __attribute__((address_space(1))) void*)g,
      (__attribute__((address_space(3))) void*)l, 16, 0, 0);
}

// round-to-nearest-even fp32 -> bf16; returns bits, sets hi to the rounded fp32 value
__device__ __forceinline__ unsigned short bfsplit(float f, float& hi) {
  unsigned u = __float_as_uint(f);
  unsigned r = (u + 0x7FFFu + ((u >> 16) & 1u)) >> 16;
  hi = __uint_as_float(r << 16);
  return (unsigned short)r;
}

// ---------------- prep x: fp32 -> (hi,lo) bf16 pair; also zero flags ----------------
__global__ __launch_bounds__(256) void vq_prep_x(const float* __restrict__ x,
                                                 unsigned short* __restrict__ xh,
                                                 unsigned short* __restrict__ xl,
                                                 int* __restrict__ flags) {
  size_t base = ((size_t)blockIdx.x * 256 + threadIdx.x) * 16;
#pragma unroll
  for (int q = 0; q < 4; ++q) {
    float4 v = *reinterpret_cast<const float4*>(x + base + q * 4);
    ushort4 h, l;
    float t, d;
    h.x = bfsplit(v.x, t); l.x = bfsplit(v.x - t, d);
    h.y = bfsplit(v.y, t); l.y = bfsplit(v.y - t, d);
    h.z = bfsplit(v.z, t); l.z = bfsplit(v.z - t, d);
    h.w = bfsplit(v.w, t); l.w = bfsplit(v.w - t, d);
    *reinterpret_cast<ushort4*>(xh + base + q * 4) = h;
    *reinterpret_cast<ushort4*>(xl + base + q * 4) = l;
  }
  if (blockIdx.x < 128) flags[blockIdx.x * 256 + threadIdx.x] = 0;
}

// ---------------- prep cb: split + hc[k] = 0.5*|c_k|^2 (fp32-exact) ----------------
__global__ __launch_bounds__(256) void vq_prep_cb(const float* __restrict__ cb,
                                                  unsigned short* __restrict__ cbh,
                                                  unsigned short* __restrict__ cbl,
                                                  float* __restrict__ hc) {
  int w = threadIdx.x >> 6, lane = threadIdx.x & 63;
  int row = blockIdx.x * 4 + w;
  size_t off = (size_t)row * 256 + lane * 4;
  float4 v = *reinterpret_cast<const float4*>(cb + off);
  ushort4 h, l;
  float t, d;
  h.x = bfsplit(v.x, t); l.x = bfsplit(v.x - t, d);
  h.y = bfsplit(v.y, t); l.y = bfsplit(v.y - t, d);
  h.z = bfsplit(v.z, t); l.z = bfsplit(v.z - t, d);
  h.w = bfsplit(v.w, t); l.w = bfsplit(v.w - t, d);
  *reinterpret_cast<ushort4*>(cbh + off) = h;
  *reinterpret_cast<ushort4*>(cbl + off) = l;
  float s = v.x * v.x + v.y * v.y + v.z * v.z + v.w * v.w;
#pragma unroll
  for (int m = 32; m >= 1; m >>= 1) s += __shfl_xor(s, m, 64);
  if (lane == 0) hc[row] = 0.5f * s;
}

// ---------------- main: 3-product split-bf16 MFMA GEMM + best/second argmax --------
// 512 thr = 8 waves (2M x 4N), wave tile 64 rows x 64 cols, block 128 rows x 1024 codes
// (4 chunks of 256). BK=32 (one mfma K). LDS: dbuf (Ah,Al 8K + Bh,Bl 16K each) = 96KB.
// Code dim spans l15 (16 lanes) x wc (4 waves): within-wave shfl merge + cross-wave
// LDS merge (R3 bug: waves raced on out[]).
__global__ __launch_bounds__(512, 2) void vq_mfma_kernel(
    const unsigned short* __restrict__ xh, const unsigned short* __restrict__ xl,
    const unsigned short* __restrict__ cbh, const unsigned short* __restrict__ cbl,
    const float* __restrict__ hc, int* __restrict__ out, int* __restrict__ flags) {
  __shared__ unsigned short sm[49152];  // 96 KB
  __shared__ float c2s[1024];           // 4 KB
  __shared__ float cbv[4][128];         // cross-wave merge: best
  __shared__ int   cbi[4][128];         //   index
  __shared__ float csv[4][128];         //   second-best

  const int tid = threadIdx.x;
  const int lane = tid & 63;
  const int wave = tid >> 6;
  const int wr = wave >> 2;   // 0..1 (M)
  const int wc = wave & 3;    // 0..3 (N)
  const int l15 = lane & 15;
  const int l4  = lane >> 4;  // 0..3
  const int r0 = blockIdx.x * 128;

  reinterpret_cast<float2*>(c2s)[tid] = reinterpret_cast<const float2*>(hc)[tid];

  // staging: row = tid>>2, stored chunk = tid&3 (linear dest). Source chunk is
  // pre-swizzled by ((row>>1)&3) so reads can XOR the same way (bank spread).
  const int srow = tid >> 2;
  const int sch  = (tid & 3) ^ ((tid >> 3) & 3);

  auto stage = [&](int T1) {
    const int p = T1 & 1;
    const int n0 = (T1 >> 3) << 8;
    const int d0 = (T1 & 7) << 5;
    unsigned short* Ah = sm + p * 4096;
    unsigned short* Al = sm + 8192 + p * 4096;
    unsigned short* Bh = sm + 16384 + p * 8192;
    unsigned short* Bl = sm + 32768 + p * 8192;
    glds16(xh + (size_t)(r0 + srow) * 256 + d0 + sch * 8, Ah + tid * 8);
    glds16(xl + (size_t)(r0 + srow) * 256 + d0 + sch * 8, Al + tid * 8);
#pragma unroll
    for (int r = 0; r < 2; ++r) {
      int idx = r * 512 + tid;
      int bch = (idx & 3) ^ ((idx >> 3) & 3);
      glds16(cbh + (size_t)(n0 + (idx >> 2)) * 256 + d0 + bch * 8, Bh + idx * 8);
    }
#pragma unroll
    for (int r = 0; r < 2; ++r) {
      int idx = r * 512 + tid;
      int bch = (idx & 3) ^ ((idx >> 3) & 3);
      glds16(cbl + (size_t)(n0 + (idx >> 2)) * 256 + d0 + bch * 8, Bl + idx * 8);
    }
  };

  float bestv[4][4], secondv[4][4];
  int besti[4][4];
#pragma unroll
  for (int tr = 0; tr < 4; ++tr)
#pragma unroll
    for (int g = 0; g < 4; ++g) {
      bestv[tr][g] = -3.4e38f; secondv[tr][g] = -3.4e38f; besti[tr][g] = 0;
    }

  stage(0);

  const int swzf = (l15 >> 1) & 3;  // read-side chunk XOR ((arow>>1)&3 == (l15>>1)&3)

  int T = 0;
  for (int nt = 0; nt < 4; ++nt) {
    f32x4 acc[4][4];
#pragma unroll
    for (int tr = 0; tr < 4; ++tr)
#pragma unroll
      for (int tc = 0; tc < 4; ++tc) acc[tr][tc] = (f32x4){0.f, 0.f, 0.f, 0.f};

    for (int dt = 0; dt < 8; ++dt, ++T) {
      const int p = T & 1;
      if (T < 31) {
        stage(T + 1);
        asm volatile("s_waitcnt vmcnt(6)" ::: "memory");
      } else {
        asm volatile("s_waitcnt vmcnt(0)" ::: "memory");
      }
      __builtin_amdgcn_s_barrier();

      const unsigned short* Ah = sm + p * 4096;
      const unsigned short* Al = sm + 8192 + p * 4096;
      const unsigned short* Bh = sm + 16384 + p * 8192;
      const unsigned short* Bl = sm + 32768 + p * 8192;

      short8v ah[4], al[4], bh[4], bl[4];
#pragma unroll
      for (int tr = 0; tr < 4; ++tr) {
        int arow = wr * 64 + tr * 16 + l15;
        ah[tr] = *reinterpret_cast<const short8v*>(Ah + arow * 32 + (l4 ^ swzf) * 8);
        al[tr] = *reinterpret_cast<const short8v*>(Al + arow * 32 + (l4 ^ swzf) * 8);
      }
#pragma unroll
      for (int tc = 0; tc < 4; ++tc) {
        int bcol = wc * 64 + tc * 16 + l15;
        bh[tc] = *reinterpret_cast<const short8v*>(Bh + bcol * 32 + (l4 ^ swzf) * 8);
        bl[tc] = *reinterpret_cast<const short8v*>(Bl + bcol * 32 + (l4 ^ swzf) * 8);
      }

#pragma unroll
      for (int tr = 0; tr < 4; ++tr)
#pragma unroll
        for (int tc = 0; tc < 4; ++tc) {
          acc[tr][tc] = __builtin_amdgcn_mfma_f32_16x16x32_bf16(ah[tr], bh[tc], acc[tr][tc], 0, 0, 0);
          acc[tr][tc] = __builtin_amdgcn_mfma_f32_16x16x32_bf16(ah[tr], bl[tc], acc[tr][tc], 0, 0, 0);
          acc[tr][tc] = __builtin_amdgcn_mfma_f32_16x16x32_bf16(al[tr], bh[tc], acc[tr][tc], 0, 0, 0);
        }

      asm volatile("s_waitcnt lgkmcnt(0)" ::: "memory");
      __builtin_amdgcn_s_barrier();
    }

    // fold chunk scores into running best/second (codes ascending per thread)
    const int cb0 = nt * 256 + wc * 64 + l15;
    float hcv[4];
#pragma unroll
    for (int tc = 0; tc < 4; ++tc) hcv[tc] = c2s[cb0 + tc * 16];
#pragma unroll
    for (int tr = 0; tr < 4; ++tr)
#pragma unroll
      for (int tc = 0; tc < 4; ++tc) {
        const int code = cb0 + tc * 16;
#pragma unroll
        for (int g = 0; g < 4; ++g) {
          float s = acc[tr][tc][g] - hcv[tc];
          bool gt = s > bestv[tr][g];
          float ns = gt ? bestv[tr][g] : fmaxf(secondv[tr][g], s);
          bestv[tr][g] = gt ? s : bestv[tr][g];
          besti[tr][g] = gt ? code : besti[tr][g];
          secondv[tr][g] = ns;
        }
      }
  }

  // within-wave merge across the 16 l15-lanes sharing each row-slot
#pragma unroll
  for (int tr = 0; tr < 4; ++tr)
#pragma unroll
    for (int g = 0; g < 4; ++g) {
      float bv = bestv[tr][g]; int bi = besti[tr][g]; float sv = secondv[tr][g];
#pragma unroll
      for (int m = 1; m < 16; m <<= 1) {
        float ov = __shfl_xor(bv, m, 64);
        int   oi = __shfl_xor(bi, m, 64);
        float os = __shfl_xor(sv, m, 64);
        sv = fmaxf(fmaxf(sv, os), fminf(bv, ov));
        bool gt = (ov > bv) || (ov == bv && oi < bi);
        bv = gt ? ov : bv;
        bi = gt ? oi : bi;
      }
      if (l15 == 0) {
        int rl = wr * 64 + tr * 16 + l4 * 4 + g;
        cbv[wc][rl] = bv; cbi[wc][rl] = bi; csv[wc][rl] = sv;
      }
    }

  // cross-wave merge: each of 4 wc-waves surveyed a disjoint 64-code slice per chunk
  __syncthreads();
  if (tid < 128) {
    float bv = cbv[0][tid]; int bi = cbi[0][tid]; float sv = csv[0][tid];
#pragma unroll
    for (int w2 = 1; w2 < 4; ++w2) {
      float ov = cbv[w2][tid]; int oi = cbi[w2][tid]; float os = csv[w2][tid];
      sv = fmaxf(fmaxf(sv, os), fminf(bv, ov));
      bool gt = (ov > bv) || (ov == bv && oi < bi);
      bv = gt ? ov : bv;
      bi = gt ? oi : bi;
    }
    out[r0 + tid] = bi;
    flags[r0 + tid] = (sv >= bv - MARG) ? 1 : 0;
  }
}

// ---------------- cleanup: exact fp32 recompute for flagged rows ----------------
__global__ __launch_bounds__(256) void vq_cleanup(const float* __restrict__ x,
                                                  const float* __restrict__ cb,
                                                  const float* __restrict__ hc,
                                                  const int* __restrict__ flags,
                                                  int* __restrict__ out) {
  const int tid = threadIdx.x;
  __shared__ float xrow[256];
  __shared__ float wv[4];
  __shared__ int wi[4];
  for (int rr = 0; rr < 128; ++rr) {
    int row = blockIdx.x * 128 + rr;
    if (flags[row] == 0) continue;  // uniform per block
    __syncthreads();
    xrow[tid] = x[(size_t)row * 256 + tid];
    __syncthreads();
    float bv = -3.4e38f; int bi = 0;
    for (int c4 = 0; c4 < 4; ++c4) {
      int code = c4 * 256 + tid;
      const float* crow = cb + (size_t)code * 256;
      float s = 0.f;
#pragma unroll 8
      for (int d = 0; d < 256; d += 4) {
        float4 c = *reinterpret_cast<const float4*>(crow + d);
        s = fmaf(xrow[d], c.x, s);
        s = fmaf(xrow[d + 1], c.y, s);
        s = fmaf(xrow[d + 2], c.z, s);
        s = fmaf(xrow[d + 3], c.w, s);
      }
      s -= hc[code];
      if (s > bv || (s == bv && code < bi)) { bv = s; bi = code; }
    }
#pragma unroll
    for (int m = 1; m < 64; m <<= 1) {
      float ov = __shfl_xor(bv, m, 64);
      int oi = __shfl_xor(bi, m, 64);
      if (ov > bv || (ov == bv && oi < bi)) { bv = ov; bi = oi; }
    }
    if ((tid & 63) == 0) { wv[tid >> 6] = bv; wi[tid >> 6] = bi; }
    __syncthreads();
    if (tid == 0) {
      for (int w2 = 1; w2 < 4; ++w2)
        if (wv[w2] > bv || (wv[w2] == bv && wi[w2] < bi)) { bv = wv[w2]; bi = wi[w2]; }
      out[row] = bi;
    }
  }
}

// ================= fallback fp32 path (R2 kernel) if ws is too small =================
#define BM 128
#define BN 256
#define BD 32
#define NT 512

__global__ __launch_bounds__(256) void vq_c2_kernel(const float* __restrict__ cb,
                                                    float* __restrict__ halfc2) {
  int row  = blockIdx.x * 4 + (threadIdx.x >> 6);
  int lane = threadIdx.x & 63;
  float4 v = *reinterpret_cast<const float4*>(cb + (size_t)row * 256 + lane * 4);
  float s = v.x * v.x + v.y * v.y + v.z * v.z + v.w * v.w;
#pragma unroll
  for (int m = 32; m >= 1; m >>= 1) s += __shfl_xor(s, m, 64);
  if (lane == 0) halfc2[row] = 0.5f * s;
}

__global__ __launch_bounds__(NT, 2) void vq_argmin_kernel(
    const float* __restrict__ x, const float* __restrict__ cb,
    const float* __restrict__ halfc2, int* __restrict__ out) {
  __shared__ float lds[2][(BM + BN) * BD];
  __shared__ float c2s[1024];
  const int tid = threadIdx.x;
  const int w   = tid >> 6;
  const int tc  = tid & 31;
  const int tr  = tid >> 5;
  const int r0  = blockIdx.x * BM;
  reinterpret_cast<float2*>(c2s)[tid] = reinterpret_cast<const float2*>(halfc2)[tid];
  const int sA  = tr & 7;
  const int sB  = tc & 7;
  const int sAB = sA ^ sB;
  const int cho = (((tid & 7) ^ w)) * 4;
  const int sub = tid >> 3;
  float bestv[8]; int besti[8];
#pragma unroll
  for (int i = 0; i < 8; ++i) { bestv[i] = -3.4e38f; besti[i] = 0; }
  auto stage = [&](int n0, int d0, int p) {
    float* dst  = &lds[p][0];
    float* dstB = dst + BM * BD;
#pragma unroll
    for (int r = 0; r < 2; ++r) {
      int t2 = r * NT + tid;
      glds16(x + (size_t)(r0 + r * 64 + sub) * 256 + d0 + cho, dst + t2 * 4);
    }
#pragma unroll
    for (int r = 0; r < 4; ++r) {
      int t2 = r * NT + tid;
      glds16(cb + (size_t)(n0 + r * 64 + sub) * 256 + d0 + cho, dstB + t2 * 4);
    }
  };
  stage(0, 0, 0);
  int t = 0;
  for (int nt = 0; nt < 4; ++nt) {
    float acc[8][8];
#pragma unroll
    for (int i = 0; i < 8; ++i)
#pragma unroll
      for (int j = 0; j < 8; ++j) acc[i][j] = 0.f;
    for (int dt = 0; dt < 8; ++dt, ++t) {
      const int p = t & 1;
      if (t < 31) {
        const int t1 = t + 1;
        stage((t1 >> 3) * BN, (t1 & 7) * BD, t1 & 1);
        asm volatile("s_waitcnt vmcnt(6)" ::: "memory");
      } else {
        asm volatile("s_waitcnt vmcnt(0)" ::: "memory");
      }
      __builtin_amdgcn_s_barrier();
      const float* pA = &lds[p][tr * 8 * BD];
      const float* pB = &lds[p][BM * BD + tc * 8 * BD];
#pragma unroll
      for (int cc = 0; cc < 8; ++cc) {
        const float* pBc = pB + ((cc ^ sAB) << 2);
        float4 a[8], b[8];
#pragma unroll
        for (int i = 0; i < 8; ++i)
          a[i] = *reinterpret_cast<const float4*>(pA + i * BD + cc * 4);
#pragma unroll
        for (int j = 0; j < 8; ++j)
          b[j] = *reinterpret_cast<const float4*>(pBc + j * BD);
#pragma unroll
        for (int i = 0; i < 8; ++i)
#pragma unroll
          for (int j = 0; j < 8; ++j) {
            acc[i][j] = fmaf(a[i].x, b[j].x, acc[i][j]);
            acc[i][j] = fmaf(a[i].y, b[j].y, acc[i][j]);
            acc[i][j] = fmaf(a[i].z, b[j].z, acc[i][j]);
            acc[i][j] = fmaf(a[i].w, b[j].w, acc[i][j]);
          }
      }
      asm volatile("s_waitcnt lgkmcnt(0)" ::: "memory");
      __builtin_amdgcn_s_barrier();
    }
    const int n0 = nt * BN;
#pragma unroll
    for (int j = 0; j < 8; ++j) {
      const int code = n0 + tc * 8 + j;
      const float hc = c2s[code];
#pragma unroll
      for (int i = 0; i < 8; ++i) {
        float s = acc[i][j] - hc;
        if (s > bestv[i]) { bestv[i] = s; besti[i] = code; }
      }
    }
  }
#pragma unroll
  for (int i = 0; i < 8; ++i) {
#pragma unroll
    for (int m = 1; m <= 16; m <<= 1) {
      float ov = __shfl_xor(bestv[i], m, 64);
      int   oi = __shfl_xor(besti[i], m, 64);
      if (ov > bestv[i] || (ov == bestv[i] && oi < besti[i])) { bestv[i] = ov; besti[i] = oi; }
    }
  }
  if (tc == 0) {
#pragma unroll
    for (int i = 0; i < 8; ++i) out[r0 + tr * 8 + i] = besti[i];
  }
}

// ==================================== launch ====================================
extern "C" void kernel_launch(void* const* d_in, const int* in_sizes, int n_in,
                              void* d_out, int out_size, void* d_ws, size_t ws_size,
                              hipStream_t stream) {
  const float* x  = (const float*)d_in[0];   // (8,4096,256) fp32
  const float* cb = (const float*)d_in[1];   // (1024,256) fp32
  int* out = (int*)d_out;                    // (8,4096) int32

  // ws layout (bytes): xh 16M | xl 16M | cbh 512K | cbl 512K | hc 4K | flags 128K
  const size_t OFF_XH = 0;
  const size_t OFF_XL = OFF_XH + (size_t)32768 * 256 * 2;
  const size_t OFF_CH = OFF_XL + (size_t)32768 * 256 * 2;
  const size_t OFF_CL = OFF_CH + (size_t)1024 * 256 * 2;
  const size_t OFF_HC = OFF_CL + (size_t)1024 * 256 * 2;
  const size_t OFF_FL = OFF_HC + (size_t)1024 * 4;
  const size_t NEED   = OFF_FL + (size_t)32768 * 4;

  if (ws_size >= NEED) {
    unsigned short* xh  = (unsigned short*)((char*)d_ws + OFF_XH);
    unsigned short* xl  = (unsigned short*)((char*)d_ws + OFF_XL);
    unsigned short* cbh = (unsigned short*)((char*)d_ws + OFF_CH);
    unsigned short* cbl = (unsigned short*)((char*)d_ws + OFF_CL);
    float* hc  = (float*)((char*)d_ws + OFF_HC);
    int* flags = (int*)((char*)d_ws + OFF_FL);

    hipLaunchKernelGGL(vq_prep_x, dim3(2048), dim3(256), 0, stream, x, xh, xl, flags);
    hipLaunchKernelGGL(vq_prep_cb, dim3(256), dim3(256), 0, stream, cb, cbh, cbl, hc);
    hipLaunchKernelGGL(vq_mfma_kernel, dim3(256), dim3(512), 0, stream,
                       xh, xl, cbh, cbl, hc, out, flags);
    hipLaunchKernelGGL(vq_cleanup, dim3(256), dim3(256), 0, stream, x, cb, hc, flags, out);
  } else {
    float* c2 = (float*)d_ws;
    hipLaunchKernelGGL(vq_c2_kernel, dim3(256), dim3(256), 0, stream, cb, c2);
    hipLaunchKernelGGL(vq_argmin_kernel, dim3(32768 / BM), dim3(NT), 0, stream,
                       x, cb, c2, out);
  }
}

// Round 5
// 167.547 us; speedup vs baseline: 1.3989x; 1.3989x over previous
//
#include <hip/hip_runtime.h>
#include <stdint.h>

typedef __attribute__((ext_vector_type(8))) short short8v;
typedef __attribute__((ext_vector_type(4))) float f32x4;

#define MARG 0.0625f

// async global->LDS, 16B per lane
__device__ __forceinline__ void glds16(const void* g, void* l) {
  __builtin_amdgcn_global_load_lds(
      (const __attribute__((address_space(1))) void*)g,
      (__attribute__((address_space(3))) void*)l, 16, 0, 0);
}

// round-to-nearest-even fp32 -> bf16; returns bits, sets hi to the rounded fp32 value
__device__ __forceinline__ unsigned short bfsplit(float f, float& hi) {
  unsigned u = __float_as_uint(f);
  unsigned r = (u + 0x7FFFu + ((u >> 16) & 1u)) >> 16;
  hi = __uint_as_float(r << 16);
  return (unsigned short)r;
}

// ---------------- prep x: fp32 -> (hi,lo) bf16 pair; also zero flag counter --------
__global__ __launch_bounds__(256) void vq_prep_x(const float* __restrict__ x,
                                                 unsigned short* __restrict__ xh,
                                                 unsigned short* __restrict__ xl,
                                                 int* __restrict__ count) {
  size_t base = ((size_t)blockIdx.x * 256 + threadIdx.x) * 16;
#pragma unroll
  for (int q = 0; q < 4; ++q) {
    float4 v = *reinterpret_cast<const float4*>(x + base + q * 4);
    ushort4 h, l;
    float t, d;
    h.x = bfsplit(v.x, t); l.x = bfsplit(v.x - t, d);
    h.y = bfsplit(v.y, t); l.y = bfsplit(v.y - t, d);
    h.z = bfsplit(v.z, t); l.z = bfsplit(v.z - t, d);
    h.w = bfsplit(v.w, t); l.w = bfsplit(v.w - t, d);
    *reinterpret_cast<ushort4*>(xh + base + q * 4) = h;
    *reinterpret_cast<ushort4*>(xl + base + q * 4) = l;
  }
  if (blockIdx.x == 0 && threadIdx.x == 0) *count = 0;
}

// ---------------- prep cb: split + hc[k] = 0.5*|c_k|^2 (fp32-exact) ----------------
__global__ __launch_bounds__(256) void vq_prep_cb(const float* __restrict__ cb,
                                                  unsigned short* __restrict__ cbh,
                                                  unsigned short* __restrict__ cbl,
                                                  float* __restrict__ hc) {
  int w = threadIdx.x >> 6, lane = threadIdx.x & 63;
  int row = blockIdx.x * 4 + w;
  size_t off = (size_t)row * 256 + lane * 4;
  float4 v = *reinterpret_cast<const float4*>(cb + off);
  ushort4 h, l;
  float t, d;
  h.x = bfsplit(v.x, t); l.x = bfsplit(v.x - t, d);
  h.y = bfsplit(v.y, t); l.y = bfsplit(v.y - t, d);
  h.z = bfsplit(v.z, t); l.z = bfsplit(v.z - t, d);
  h.w = bfsplit(v.w, t); l.w = bfsplit(v.w - t, d);
  *reinterpret_cast<ushort4*>(cbh + off) = h;
  *reinterpret_cast<ushort4*>(cbl + off) = l;
  float s = v.x * v.x + v.y * v.y + v.z * v.z + v.w * v.w;
#pragma unroll
  for (int m = 32; m >= 1; m >>= 1) s += __shfl_xor(s, m, 64);
  if (lane == 0) hc[row] = 0.5f * s;
}

// ---------------- main: 3-product split-bf16 MFMA GEMM + best/second argmax --------
// 512 thr = 8 waves (2M x 4N), wave tile 64 rows x 64 cols, block 128 rows x 1024 codes
// (4 chunks of 256). BK=32 (one mfma K). LDS: dbuf (Ah,Al 8K + Bh,Bl 16K each) = 96KB.
// Ambiguous rows (second within MARG of best) are appended to a compact list.
__global__ __launch_bounds__(512, 2) void vq_mfma_kernel(
    const unsigned short* __restrict__ xh, const unsigned short* __restrict__ xl,
    const unsigned short* __restrict__ cbh, const unsigned short* __restrict__ cbl,
    const float* __restrict__ hc, int* __restrict__ out,
    int* __restrict__ list, int* __restrict__ count) {
  __shared__ unsigned short sm[49152];  // 96 KB
  __shared__ float c2s[1024];           // 4 KB
  __shared__ float cbv[4][128];         // cross-wave merge: best
  __shared__ int   cbi[4][128];         //   index
  __shared__ float csv[4][128];         //   second-best

  const int tid = threadIdx.x;
  const int lane = tid & 63;
  const int wave = tid >> 6;
  const int wr = wave >> 2;   // 0..1 (M)
  const int wc = wave & 3;    // 0..3 (N)
  const int l15 = lane & 15;
  const int l4  = lane >> 4;  // 0..3
  const int r0 = blockIdx.x * 128;

  reinterpret_cast<float2*>(c2s)[tid] = reinterpret_cast<const float2*>(hc)[tid];

  // staging: row = tid>>2, stored chunk = tid&3 (linear dest). Source chunk is
  // pre-swizzled by ((row>>1)&3) so reads can XOR the same way (bank spread).
  const int srow = tid >> 2;
  const int sch  = (tid & 3) ^ ((tid >> 3) & 3);

  auto stage = [&](int T1) {
    const int p = T1 & 1;
    const int n0 = (T1 >> 3) << 8;
    const int d0 = (T1 & 7) << 5;
    unsigned short* Ah = sm + p * 4096;
    unsigned short* Al = sm + 8192 + p * 4096;
    unsigned short* Bh = sm + 16384 + p * 8192;
    unsigned short* Bl = sm + 32768 + p * 8192;
    glds16(xh + (size_t)(r0 + srow) * 256 + d0 + sch * 8, Ah + tid * 8);
    glds16(xl + (size_t)(r0 + srow) * 256 + d0 + sch * 8, Al + tid * 8);
#pragma unroll
    for (int r = 0; r < 2; ++r) {
      int idx = r * 512 + tid;
      int bch = (idx & 3) ^ ((idx >> 3) & 3);
      glds16(cbh + (size_t)(n0 + (idx >> 2)) * 256 + d0 + bch * 8, Bh + idx * 8);
    }
#pragma unroll
    for (int r = 0; r < 2; ++r) {
      int idx = r * 512 + tid;
      int bch = (idx & 3) ^ ((idx >> 3) & 3);
      glds16(cbl + (size_t)(n0 + (idx >> 2)) * 256 + d0 + bch * 8, Bl + idx * 8);
    }
  };

  float bestv[4][4], secondv[4][4];
  int besti[4][4];
#pragma unroll
  for (int tr = 0; tr < 4; ++tr)
#pragma unroll
    for (int g = 0; g < 4; ++g) {
      bestv[tr][g] = -3.4e38f; secondv[tr][g] = -3.4e38f; besti[tr][g] = 0;
    }

  stage(0);

  const int swzf = (l15 >> 1) & 3;  // read-side chunk XOR ((arow>>1)&3 == (l15>>1)&3)

  int T = 0;
  for (int nt = 0; nt < 4; ++nt) {
    f32x4 acc[4][4];
#pragma unroll
    for (int tr = 0; tr < 4; ++tr)
#pragma unroll
      for (int tc = 0; tc < 4; ++tc) acc[tr][tc] = (f32x4){0.f, 0.f, 0.f, 0.f};

    for (int dt = 0; dt < 8; ++dt, ++T) {
      const int p = T & 1;
      if (T < 31) {
        stage(T + 1);
        asm volatile("s_waitcnt vmcnt(6)" ::: "memory");
      } else {
        asm volatile("s_waitcnt vmcnt(0)" ::: "memory");
      }
      __builtin_amdgcn_s_barrier();

      const unsigned short* Ah = sm + p * 4096;
      const unsigned short* Al = sm + 8192 + p * 4096;
      const unsigned short* Bh = sm + 16384 + p * 8192;
      const unsigned short* Bl = sm + 32768 + p * 8192;

      short8v ah[4], al[4], bh[4], bl[4];
#pragma unroll
      for (int tr = 0; tr < 4; ++tr) {
        int arow = wr * 64 + tr * 16 + l15;
        ah[tr] = *reinterpret_cast<const short8v*>(Ah + arow * 32 + (l4 ^ swzf) * 8);
        al[tr] = *reinterpret_cast<const short8v*>(Al + arow * 32 + (l4 ^ swzf) * 8);
      }
#pragma unroll
      for (int tc = 0; tc < 4; ++tc) {
        int bcol = wc * 64 + tc * 16 + l15;
        bh[tc] = *reinterpret_cast<const short8v*>(Bh + bcol * 32 + (l4 ^ swzf) * 8);
        bl[tc] = *reinterpret_cast<const short8v*>(Bl + bcol * 32 + (l4 ^ swzf) * 8);
      }

#pragma unroll
      for (int tr = 0; tr < 4; ++tr)
#pragma unroll
        for (int tc = 0; tc < 4; ++tc) {
          acc[tr][tc] = __builtin_amdgcn_mfma_f32_16x16x32_bf16(ah[tr], bh[tc], acc[tr][tc], 0, 0, 0);
          acc[tr][tc] = __builtin_amdgcn_mfma_f32_16x16x32_bf16(ah[tr], bl[tc], acc[tr][tc], 0, 0, 0);
          acc[tr][tc] = __builtin_amdgcn_mfma_f32_16x16x32_bf16(al[tr], bh[tc], acc[tr][tc], 0, 0, 0);
        }

      asm volatile("s_waitcnt lgkmcnt(0)" ::: "memory");
      __builtin_amdgcn_s_barrier();
    }

    // fold chunk scores into running best/second (codes ascending per thread)
    const int cb0 = nt * 256 + wc * 64 + l15;
    float hcv[4];
#pragma unroll
    for (int tc = 0; tc < 4; ++tc) hcv[tc] = c2s[cb0 + tc * 16];
#pragma unroll
    for (int tr = 0; tr < 4; ++tr)
#pragma unroll
      for (int tc = 0; tc < 4; ++tc) {
        const int code = cb0 + tc * 16;
#pragma unroll
        for (int g = 0; g < 4; ++g) {
          float s = acc[tr][tc][g] - hcv[tc];
          bool gt = s > bestv[tr][g];
          float ns = gt ? bestv[tr][g] : fmaxf(secondv[tr][g], s);
          bestv[tr][g] = gt ? s : bestv[tr][g];
          besti[tr][g] = gt ? code : besti[tr][g];
          secondv[tr][g] = ns;
        }
      }
  }

  // within-wave merge across the 16 l15-lanes sharing each row-slot
#pragma unroll
  for (int tr = 0; tr < 4; ++tr)
#pragma unroll
    for (int g = 0; g < 4; ++g) {
      float bv = bestv[tr][g]; int bi = besti[tr][g]; float sv = secondv[tr][g];
#pragma unroll
      for (int m = 1; m < 16; m <<= 1) {
        float ov = __shfl_xor(bv, m, 64);
        int   oi = __shfl_xor(bi, m, 64);
        float os = __shfl_xor(sv, m, 64);
        sv = fmaxf(fmaxf(sv, os), fminf(bv, ov));
        bool gt = (ov > bv) || (ov == bv && oi < bi);
        bv = gt ? ov : bv;
        bi = gt ? oi : bi;
      }
      if (l15 == 0) {
        int rl = wr * 64 + tr * 16 + l4 * 4 + g;
        cbv[wc][rl] = bv; cbi[wc][rl] = bi; csv[wc][rl] = sv;
      }
    }

  // cross-wave merge: each of 4 wc-waves surveyed a disjoint 64-code slice per chunk
  __syncthreads();
  if (tid < 128) {
    float bv = cbv[0][tid]; int bi = cbi[0][tid]; float sv = csv[0][tid];
#pragma unroll
    for (int w2 = 1; w2 < 4; ++w2) {
      float ov = cbv[w2][tid]; int oi = cbi[w2][tid]; float os = csv[w2][tid];
      sv = fmaxf(fmaxf(sv, os), fminf(bv, ov));
      bool gt = (ov > bv) || (ov == bv && oi < bi);
      bv = gt ? ov : bv;
      bi = gt ? oi : bi;
    }
    out[r0 + tid] = bi;
    if (sv >= bv - MARG) {           // ambiguous: append to compact recheck list
      int slot = atomicAdd(count, 1);
      list[slot] = r0 + tid;
    }
  }
}

// ---------------- cleanup: exact fp32 recompute for listed rows only ----------------
__global__ __launch_bounds__(256) void vq_cleanup(const float* __restrict__ x,
                                                  const float* __restrict__ cb,
                                                  const float* __restrict__ hc,
                                                  const int* __restrict__ list,
                                                  const int* __restrict__ count,
                                                  int* __restrict__ out) {
  const int tid = threadIdx.x;
  __shared__ float xrow[256];
  __shared__ float wv[4];
  __shared__ int wi[4];
  const int n = *count;
  for (int li = blockIdx.x; li < n; li += gridDim.x) {
    int row = list[li];
    __syncthreads();
    xrow[tid] = x[(size_t)row * 256 + tid];
    __syncthreads();
    float bv = -3.4e38f; int bi = 0;
    for (int c4 = 0; c4 < 4; ++c4) {
      int code = c4 * 256 + tid;
      const float* crow = cb + (size_t)code * 256;
      float s = 0.f;
#pragma unroll 8
      for (int d = 0; d < 256; d += 4) {
        float4 c = *reinterpret_cast<const float4*>(crow + d);
        s = fmaf(xrow[d], c.x, s);
        s = fmaf(xrow[d + 1], c.y, s);
        s = fmaf(xrow[d + 2], c.z, s);
        s = fmaf(xrow[d + 3], c.w, s);
      }
      s -= hc[code];
      if (s > bv || (s == bv && code < bi)) { bv = s; bi = code; }
    }
#pragma unroll
    for (int m = 1; m < 64; m <<= 1) {
      float ov = __shfl_xor(bv, m, 64);
      int oi = __shfl_xor(bi, m, 64);
      if (ov > bv || (ov == bv && oi < bi)) { bv = ov; bi = oi; }
    }
    if ((tid & 63) == 0) { wv[tid >> 6] = bv; wi[tid >> 6] = bi; }
    __syncthreads();
    if (tid == 0) {
      for (int w2 = 1; w2 < 4; ++w2)
        if (wv[w2] > bv || (wv[w2] == bv && wi[w2] < bi)) { bv = wv[w2]; bi = wi[w2]; }
      out[row] = bi;
    }
  }
}

// ================= fallback fp32 path (R2 kernel) if ws is too small =================
#define BM 128
#define BN 256
#define BD 32
#define NT 512

__global__ __launch_bounds__(256) void vq_c2_kernel(const float* __restrict__ cb,
                                                    float* __restrict__ halfc2) {
  int row  = blockIdx.x * 4 + (threadIdx.x >> 6);
  int lane = threadIdx.x & 63;
  float4 v = *reinterpret_cast<const float4*>(cb + (size_t)row * 256 + lane * 4);
  float s = v.x * v.x + v.y * v.y + v.z * v.z + v.w * v.w;
#pragma unroll
  for (int m = 32; m >= 1; m >>= 1) s += __shfl_xor(s, m, 64);
  if (lane == 0) halfc2[row] = 0.5f * s;
}

__global__ __launch_bounds__(NT, 2) void vq_argmin_kernel(
    const float* __restrict__ x, const float* __restrict__ cb,
    const float* __restrict__ halfc2, int* __restrict__ out) {
  __shared__ float lds[2][(BM + BN) * BD];
  __shared__ float c2s[1024];
  const int tid = threadIdx.x;
  const int w   = tid >> 6;
  const int tc  = tid & 31;
  const int tr  = tid >> 5;
  const int r0  = blockIdx.x * BM;
  reinterpret_cast<float2*>(c2s)[tid] = reinterpret_cast<const float2*>(halfc2)[tid];
  const int sA  = tr & 7;
  const int sB  = tc & 7;
  const int sAB = sA ^ sB;
  const int cho = (((tid & 7) ^ w)) * 4;
  const int sub = tid >> 3;
  float bestv[8]; int besti[8];
#pragma unroll
  for (int i = 0; i < 8; ++i) { bestv[i] = -3.4e38f; besti[i] = 0; }
  auto stage = [&](int n0, int d0, int p) {
    float* dst  = &lds[p][0];
    float* dstB = dst + BM * BD;
#pragma unroll
    for (int r = 0; r < 2; ++r) {
      int t2 = r * NT + tid;
      glds16(x + (size_t)(r0 + r * 64 + sub) * 256 + d0 + cho, dst + t2 * 4);
    }
#pragma unroll
    for (int r = 0; r < 4; ++r) {
      int t2 = r * NT + tid;
      glds16(cb + (size_t)(n0 + r * 64 + sub) * 256 + d0 + cho, dstB + t2 * 4);
    }
  };
  stage(0, 0, 0);
  int t = 0;
  for (int nt = 0; nt < 4; ++nt) {
    float acc[8][8];
#pragma unroll
    for (int i = 0; i < 8; ++i)
#pragma unroll
      for (int j = 0; j < 8; ++j) acc[i][j] = 0.f;
    for (int dt = 0; dt < 8; ++dt, ++t) {
      const int p = t & 1;
      if (t < 31) {
        const int t1 = t + 1;
        stage((t1 >> 3) * BN, (t1 & 7) * BD, t1 & 1);
        asm volatile("s_waitcnt vmcnt(6)" ::: "memory");
      } else {
        asm volatile("s_waitcnt vmcnt(0)" ::: "memory");
      }
      __builtin_amdgcn_s_barrier();
      const float* pA = &lds[p][tr * 8 * BD];
      const float* pB = &lds[p][BM * BD + tc * 8 * BD];
#pragma unroll
      for (int cc = 0; cc < 8; ++cc) {
        const float* pBc = pB + ((cc ^ sAB) << 2);
        float4 a[8], b[8];
#pragma unroll
        for (int i = 0; i < 8; ++i)
          a[i] = *reinterpret_cast<const float4*>(pA + i * BD + cc * 4);
#pragma unroll
        for (int j = 0; j < 8; ++j)
          b[j] = *reinterpret_cast<const float4*>(pBc + j * BD);
#pragma unroll
        for (int i = 0; i < 8; ++i)
#pragma unroll
          for (int j = 0; j < 8; ++j) {
            acc[i][j] = fmaf(a[i].x, b[j].x, acc[i][j]);
            acc[i][j] = fmaf(a[i].y, b[j].y, acc[i][j]);
            acc[i][j] = fmaf(a[i].z, b[j].z, acc[i][j]);
            acc[i][j] = fmaf(a[i].w, b[j].w, acc[i][j]);
          }
      }
      asm volatile("s_waitcnt lgkmcnt(0)" ::: "memory");
      __builtin_amdgcn_s_barrier();
    }
    const int n0 = nt * BN;
#pragma unroll
    for (int j = 0; j < 8; ++j) {
      const int code = n0 + tc * 8 + j;
      const float hc = c2s[code];
#pragma unroll
      for (int i = 0; i < 8; ++i) {
        float s = acc[i][j] - hc;
        if (s > bestv[i]) { bestv[i] = s; besti[i] = code; }
      }
    }
  }
#pragma unroll
  for (int i = 0; i < 8; ++i) {
#pragma unroll
    for (int m = 1; m <= 16; m <<= 1) {
      float ov = __shfl_xor(bestv[i], m, 64);
      int   oi = __shfl_xor(besti[i], m, 64);
      if (ov > bestv[i] || (ov == bestv[i] && oi < besti[i])) { bestv[i] = ov; besti[i] = oi; }
    }
  }
  if (tc == 0) {
#pragma unroll
    for (int i = 0; i < 8; ++i) out[r0 + tr * 8 + i] = besti[i];
  }
}

// ==================================== launch ====================================
extern "C" void kernel_launch(void* const* d_in, const int* in_sizes, int n_in,
                              void* d_out, int out_size, void* d_ws, size_t ws_size,
                              hipStream_t stream) {
  const float* x  = (const float*)d_in[0];   // (8,4096,256) fp32
  const float* cb = (const float*)d_in[1];   // (1024,256) fp32
  int* out = (int*)d_out;                    // (8,4096) int32

  // ws layout (bytes): xh 16M | xl 16M | cbh 512K | cbl 512K | hc 4K | list 128K | count 4
  const size_t OFF_XH = 0;
  const size_t OFF_XL = OFF_XH + (size_t)32768 * 256 * 2;
  const size_t OFF_CH = OFF_XL + (size_t)32768 * 256 * 2;
  const size_t OFF_CL = OFF_CH + (size_t)1024 * 256 * 2;
  const size_t OFF_HC = OFF_CL + (size_t)1024 * 256 * 2;
  const size_t OFF_LS = OFF_HC + (size_t)1024 * 4;
  const size_t OFF_CT = OFF_LS + (size_t)32768 * 4;
  const size_t NEED   = OFF_CT + 64;

  if (ws_size >= NEED) {
    unsigned short* xh  = (unsigned short*)((char*)d_ws + OFF_XH);
    unsigned short* xl  = (unsigned short*)((char*)d_ws + OFF_XL);
    unsigned short* cbh = (unsigned short*)((char*)d_ws + OFF_CH);
    unsigned short* cbl = (unsigned short*)((char*)d_ws + OFF_CL);
    float* hc  = (float*)((char*)d_ws + OFF_HC);
    int* list  = (int*)((char*)d_ws + OFF_LS);
    int* count = (int*)((char*)d_ws + OFF_CT);

    hipLaunchKernelGGL(vq_prep_x, dim3(2048), dim3(256), 0, stream, x, xh, xl, count);
    hipLaunchKernelGGL(vq_prep_cb, dim3(256), dim3(256), 0, stream, cb, cbh, cbl, hc);
    hipLaunchKernelGGL(vq_mfma_kernel, dim3(256), dim3(512), 0, stream,
                       xh, xl, cbh, cbl, hc, out, list, count);
    hipLaunchKernelGGL(vq_cleanup, dim3(128), dim3(256), 0, stream,
                       x, cb, hc, list, count, out);
  } else {
    float* c2 = (float*)d_ws;
    hipLaunchKernelGGL(vq_c2_kernel, dim3(256), dim3(256), 0, stream, cb, c2);
    hipLaunchKernelGGL(vq_argmin_kernel, dim3(32768 / BM), dim3(NT), 0, stream,
                       x, cb, c2, out);
  }
}

// Round 6
// 140.711 us; speedup vs baseline: 1.6657x; 1.1907x over previous
//
#include <hip/hip_runtime.h>
#include <stdint.h>

typedef __attribute__((ext_vector_type(8))) short short8v;
typedef __attribute__((ext_vector_type(4))) float f32x4;

#define MARG 0.0625f

// async global->LDS, 16B per lane
__device__ __forceinline__ void glds16(const void* g, void* l) {
  __builtin_amdgcn_global_load_lds(
      (const __attribute__((address_space(1))) void*)g,
      (__attribute__((address_space(3))) void*)l, 16, 0, 0);
}

// round-to-nearest-even fp32 -> bf16; returns bits, sets hi to the rounded fp32 value
__device__ __forceinline__ unsigned short bfsplit(float f, float& hi) {
  unsigned u = __float_as_uint(f);
  unsigned r = (u + 0x7FFFu + ((u >> 16) & 1u)) >> 16;
  hi = __uint_as_float(r << 16);
  return (unsigned short)r;
}

// ---------------- prep x: fp32 -> (hi,lo) bf16 pair; also zero flag counter --------
__global__ __launch_bounds__(256) void vq_prep_x(const float* __restrict__ x,
                                                 unsigned short* __restrict__ xh,
                                                 unsigned short* __restrict__ xl,
                                                 int* __restrict__ count) {
  size_t base = ((size_t)blockIdx.x * 256 + threadIdx.x) * 16;
#pragma unroll
  for (int q = 0; q < 4; ++q) {
    float4 v = *reinterpret_cast<const float4*>(x + base + q * 4);
    ushort4 h, l;
    float t, d;
    h.x = bfsplit(v.x, t); l.x = bfsplit(v.x - t, d);
    h.y = bfsplit(v.y, t); l.y = bfsplit(v.y - t, d);
    h.z = bfsplit(v.z, t); l.z = bfsplit(v.z - t, d);
    h.w = bfsplit(v.w, t); l.w = bfsplit(v.w - t, d);
    *reinterpret_cast<ushort4*>(xh + base + q * 4) = h;
    *reinterpret_cast<ushort4*>(xl + base + q * 4) = l;
  }
  if (blockIdx.x == 0 && threadIdx.x == 0) *count = 0;
}

// ---------------- prep cb: split + hc[k] = 0.5*|c_k|^2 (fp32-exact) ----------------
__global__ __launch_bounds__(256) void vq_prep_cb(const float* __restrict__ cb,
                                                  unsigned short* __restrict__ cbh,
                                                  unsigned short* __restrict__ cbl,
                                                  float* __restrict__ hc) {
  int w = threadIdx.x >> 6, lane = threadIdx.x & 63;
  int row = blockIdx.x * 4 + w;
  size_t off = (size_t)row * 256 + lane * 4;
  float4 v = *reinterpret_cast<const float4*>(cb + off);
  ushort4 h, l;
  float t, d;
  h.x = bfsplit(v.x, t); l.x = bfsplit(v.x - t, d);
  h.y = bfsplit(v.y, t); l.y = bfsplit(v.y - t, d);
  h.z = bfsplit(v.z, t); l.z = bfsplit(v.z - t, d);
  h.w = bfsplit(v.w, t); l.w = bfsplit(v.w - t, d);
  *reinterpret_cast<ushort4*>(cbh + off) = h;
  *reinterpret_cast<ushort4*>(cbl + off) = l;
  float s = v.x * v.x + v.y * v.y + v.z * v.z + v.w * v.w;
#pragma unroll
  for (int m = 32; m >= 1; m >>= 1) s += __shfl_xor(s, m, 64);
  if (lane == 0) hc[row] = 0.5f * s;
}

// ---------------- main: 3-product split-bf16 MFMA GEMM + best/second argmax --------
// 512 thr = 8 waves (2M x 4N), wave tile 64 rows x 64 cols, block 128 rows x 1024 codes
// (4 chunks of 256). BK=32 (one mfma K). LDS: dbuf (Ah,Al 8K + Bh,Bl 16K each) = 96KB.
// Ambiguous rows (second within MARG of best) are appended to a compact list.
__global__ __launch_bounds__(512, 2) void vq_mfma_kernel(
    const unsigned short* __restrict__ xh, const unsigned short* __restrict__ xl,
    const unsigned short* __restrict__ cbh, const unsigned short* __restrict__ cbl,
    const float* __restrict__ hc, int* __restrict__ out,
    int* __restrict__ list, int* __restrict__ count) {
  __shared__ unsigned short sm[49152];  // 96 KB
  __shared__ float c2s[1024];           // 4 KB
  __shared__ float cbv[4][128];         // cross-wave merge: best
  __shared__ int   cbi[4][128];         //   index
  __shared__ float csv[4][128];         //   second-best

  const int tid = threadIdx.x;
  const int lane = tid & 63;
  const int wave = tid >> 6;
  const int wr = wave >> 2;   // 0..1 (M)
  const int wc = wave & 3;    // 0..3 (N)
  const int l15 = lane & 15;
  const int l4  = lane >> 4;  // 0..3
  const int r0 = blockIdx.x * 128;

  reinterpret_cast<float2*>(c2s)[tid] = reinterpret_cast<const float2*>(hc)[tid];

  // staging: row = tid>>2, stored chunk = tid&3 (linear dest). Source chunk is
  // pre-swizzled by ((row>>1)&3) so reads can XOR the same way (bank spread).
  const int srow = tid >> 2;
  const int sch  = (tid & 3) ^ ((tid >> 3) & 3);

  auto stage = [&](int T1) {
    const int p = T1 & 1;
    const int n0 = (T1 >> 3) << 8;
    const int d0 = (T1 & 7) << 5;
    unsigned short* Ah = sm + p * 4096;
    unsigned short* Al = sm + 8192 + p * 4096;
    unsigned short* Bh = sm + 16384 + p * 8192;
    unsigned short* Bl = sm + 32768 + p * 8192;
    glds16(xh + (size_t)(r0 + srow) * 256 + d0 + sch * 8, Ah + tid * 8);
    glds16(xl + (size_t)(r0 + srow) * 256 + d0 + sch * 8, Al + tid * 8);
#pragma unroll
    for (int r = 0; r < 2; ++r) {
      int idx = r * 512 + tid;
      int bch = (idx & 3) ^ ((idx >> 3) & 3);
      glds16(cbh + (size_t)(n0 + (idx >> 2)) * 256 + d0 + bch * 8, Bh + idx * 8);
    }
#pragma unroll
    for (int r = 0; r < 2; ++r) {
      int idx = r * 512 + tid;
      int bch = (idx & 3) ^ ((idx >> 3) & 3);
      glds16(cbl + (size_t)(n0 + (idx >> 2)) * 256 + d0 + bch * 8, Bl + idx * 8);
    }
  };

  float bestv[4][4], secondv[4][4];
  int besti[4][4];
#pragma unroll
  for (int tr = 0; tr < 4; ++tr)
#pragma unroll
    for (int g = 0; g < 4; ++g) {
      bestv[tr][g] = -3.4e38f; secondv[tr][g] = -3.4e38f; besti[tr][g] = 0;
    }

  stage(0);

  const int swzf = (l15 >> 1) & 3;  // read-side chunk XOR ((arow>>1)&3 == (l15>>1)&3)

  int T = 0;
  for (int nt = 0; nt < 4; ++nt) {
    f32x4 acc[4][4];
#pragma unroll
    for (int tr = 0; tr < 4; ++tr)
#pragma unroll
      for (int tc = 0; tc < 4; ++tc) acc[tr][tc] = (f32x4){0.f, 0.f, 0.f, 0.f};

    for (int dt = 0; dt < 8; ++dt, ++T) {
      const int p = T & 1;
      if (T < 31) {
        stage(T + 1);
        asm volatile("s_waitcnt vmcnt(6)" ::: "memory");
      } else {
        asm volatile("s_waitcnt vmcnt(0)" ::: "memory");
      }
      __builtin_amdgcn_s_barrier();

      const unsigned short* Ah = sm + p * 4096;
      const unsigned short* Al = sm + 8192 + p * 4096;
      const unsigned short* Bh = sm + 16384 + p * 8192;
      const unsigned short* Bl = sm + 32768 + p * 8192;

      short8v ah[4], al[4], bh[4], bl[4];
#pragma unroll
      for (int tr = 0; tr < 4; ++tr) {
        int arow = wr * 64 + tr * 16 + l15;
        ah[tr] = *reinterpret_cast<const short8v*>(Ah + arow * 32 + (l4 ^ swzf) * 8);
        al[tr] = *reinterpret_cast<const short8v*>(Al + arow * 32 + (l4 ^ swzf) * 8);
      }
#pragma unroll
      for (int tc = 0; tc < 4; ++tc) {
        int bcol = wc * 64 + tc * 16 + l15;
        bh[tc] = *reinterpret_cast<const short8v*>(Bh + bcol * 32 + (l4 ^ swzf) * 8);
        bl[tc] = *reinterpret_cast<const short8v*>(Bl + bcol * 32 + (l4 ^ swzf) * 8);
      }

#pragma unroll
      for (int tr = 0; tr < 4; ++tr)
#pragma unroll
        for (int tc = 0; tc < 4; ++tc) {
          acc[tr][tc] = __builtin_amdgcn_mfma_f32_16x16x32_bf16(ah[tr], bh[tc], acc[tr][tc], 0, 0, 0);
          acc[tr][tc] = __builtin_amdgcn_mfma_f32_16x16x32_bf16(ah[tr], bl[tc], acc[tr][tc], 0, 0, 0);
          acc[tr][tc] = __builtin_amdgcn_mfma_f32_16x16x32_bf16(al[tr], bh[tc], acc[tr][tc], 0, 0, 0);
        }

      asm volatile("s_waitcnt lgkmcnt(0)" ::: "memory");
      __builtin_amdgcn_s_barrier();
    }

    // fold chunk scores into running best/second (codes ascending per thread)
    const int cb0 = nt * 256 + wc * 64 + l15;
    float hcv[4];
#pragma unroll
    for (int tc = 0; tc < 4; ++tc) hcv[tc] = c2s[cb0 + tc * 16];
#pragma unroll
    for (int tr = 0; tr < 4; ++tr)
#pragma unroll
      for (int tc = 0; tc < 4; ++tc) {
        const int code = cb0 + tc * 16;
#pragma unroll
        for (int g = 0; g < 4; ++g) {
          float s = acc[tr][tc][g] - hcv[tc];
          bool gt = s > bestv[tr][g];
          float ns = gt ? bestv[tr][g] : fmaxf(secondv[tr][g], s);
          bestv[tr][g] = gt ? s : bestv[tr][g];
          besti[tr][g] = gt ? code : besti[tr][g];
          secondv[tr][g] = ns;
        }
      }
  }

  // within-wave merge across the 16 l15-lanes sharing each row-slot
#pragma unroll
  for (int tr = 0; tr < 4; ++tr)
#pragma unroll
    for (int g = 0; g < 4; ++g) {
      float bv = bestv[tr][g]; int bi = besti[tr][g]; float sv = secondv[tr][g];
#pragma unroll
      for (int m = 1; m < 16; m <<= 1) {
        float ov = __shfl_xor(bv, m, 64);
        int   oi = __shfl_xor(bi, m, 64);
        float os = __shfl_xor(sv, m, 64);
        sv = fmaxf(fmaxf(sv, os), fminf(bv, ov));
        bool gt = (ov > bv) || (ov == bv && oi < bi);
        bv = gt ? ov : bv;
        bi = gt ? oi : bi;
      }
      if (l15 == 0) {
        int rl = wr * 64 + tr * 16 + l4 * 4 + g;
        cbv[wc][rl] = bv; cbi[wc][rl] = bi; csv[wc][rl] = sv;
      }
    }

  // cross-wave merge: each of 4 wc-waves surveyed a disjoint 64-code slice per chunk
  __syncthreads();
  if (tid < 128) {
    float bv = cbv[0][tid]; int bi = cbi[0][tid]; float sv = csv[0][tid];
#pragma unroll
    for (int w2 = 1; w2 < 4; ++w2) {
      float ov = cbv[w2][tid]; int oi = cbi[w2][tid]; float os = csv[w2][tid];
      sv = fmaxf(fmaxf(sv, os), fminf(bv, ov));
      bool gt = (ov > bv) || (ov == bv && oi < bi);
      bv = gt ? ov : bv;
      bi = gt ? oi : bi;
    }
    out[r0 + tid] = bi;
    if (sv >= bv - MARG) {           // ambiguous: append to compact recheck list
      int slot = atomicAdd(count, 1);
      list[slot] = r0 + tid;
    }
  }
}

// -------- cleanup v2: batched exact fp32 recompute, 16 flagged rows per block ------
// Stages 16 x-rows in LDS; each thread owns codes {tid, tid+256, tid+512, tid+768}
// and streams its 4 code rows from L2 ONCE per 16-row tile (vs once per row in v1).
__global__ __launch_bounds__(256) void vq_cleanup(const float* __restrict__ x,
                                                  const float* __restrict__ cb,
                                                  const float* __restrict__ hc,
                                                  const int* __restrict__ list,
                                                  const int* __restrict__ count,
                                                  int* __restrict__ out) {
  __shared__ float xt[16][256];   // 16 KB
  __shared__ int rowids[16];
  __shared__ float wbv[4][16];
  __shared__ int   wbi[4][16];
  const int tid = threadIdx.x;
  const int n = *count;

  for (int t0 = blockIdx.x * 16; t0 < n; t0 += gridDim.x * 16) {
    __syncthreads();  // protect LDS reuse across grid-stride iterations
    if (tid < 16) rowids[tid] = (t0 + tid < n) ? list[t0 + tid] : -1;
    __syncthreads();
    {
      int j = tid >> 4, seg = tid & 15;
      int row = rowids[j];
      if (row < 0) row = rowids[0];  // dead slot: stage any valid row (result unused)
      const float4* src = reinterpret_cast<const float4*>(x + (size_t)row * 256 + seg * 16);
      float4* dst = reinterpret_cast<float4*>(&xt[j][seg * 16]);
#pragma unroll
      for (int q = 0; q < 4; ++q) dst[q] = src[q];
    }
    __syncthreads();

    float accv[4][16];
#pragma unroll
    for (int k = 0; k < 4; ++k)
#pragma unroll
      for (int j = 0; j < 16; ++j) accv[k][j] = 0.f;

#pragma unroll 2
    for (int d0 = 0; d0 < 256; d0 += 4) {
      float4 c4[4];
#pragma unroll
      for (int k = 0; k < 4; ++k)
        c4[k] = *reinterpret_cast<const float4*>(cb + (size_t)(k * 256 + tid) * 256 + d0);
#pragma unroll
      for (int j = 0; j < 16; ++j) {
        float4 xv = *reinterpret_cast<const float4*>(&xt[j][d0]);  // wave-broadcast
#pragma unroll
        for (int k = 0; k < 4; ++k) {
          accv[k][j] = fmaf(c4[k].x, xv.x, accv[k][j]);
          accv[k][j] = fmaf(c4[k].y, xv.y, accv[k][j]);
          accv[k][j] = fmaf(c4[k].z, xv.z, accv[k][j]);
          accv[k][j] = fmaf(c4[k].w, xv.w, accv[k][j]);
        }
      }
    }

    float hcv[4];
#pragma unroll
    for (int k = 0; k < 4; ++k) hcv[k] = hc[k * 256 + tid];

#pragma unroll
    for (int j = 0; j < 16; ++j) {
      float bv = accv[0][j] - hcv[0]; int bi = tid;
#pragma unroll
      for (int k = 1; k < 4; ++k) {
        float s = accv[k][j] - hcv[k];
        if (s > bv) { bv = s; bi = k * 256 + tid; }  // codes ascending in k
      }
#pragma unroll
      for (int m = 1; m < 64; m <<= 1) {
        float ov = __shfl_xor(bv, m, 64);
        int   oi = __shfl_xor(bi, m, 64);
        bool gt = (ov > bv) || (ov == bv && oi < bi);
        bv = gt ? ov : bv;
        bi = gt ? oi : bi;
      }
      if ((tid & 63) == 0) { wbv[tid >> 6][j] = bv; wbi[tid >> 6][j] = bi; }
    }
    __syncthreads();
    if (tid < 16 && rowids[tid] >= 0) {
      float bv = wbv[0][tid]; int bi = wbi[0][tid];
#pragma unroll
      for (int w2 = 1; w2 < 4; ++w2) {
        float ov = wbv[w2][tid]; int oi = wbi[w2][tid];
        if (ov > bv || (ov == bv && oi < bi)) { bv = ov; bi = oi; }
      }
      out[rowids[tid]] = bi;
    }
  }
}

// ================= fallback fp32 path (R2 kernel) if ws is too small =================
#define BM 128
#define BN 256
#define BD 32
#define NT 512

__global__ __launch_bounds__(256) void vq_c2_kernel(const float* __restrict__ cb,
                                                    float* __restrict__ halfc2) {
  int row  = blockIdx.x * 4 + (threadIdx.x >> 6);
  int lane = threadIdx.x & 63;
  float4 v = *reinterpret_cast<const float4*>(cb + (size_t)row * 256 + lane * 4);
  float s = v.x * v.x + v.y * v.y + v.z * v.z + v.w * v.w;
#pragma unroll
  for (int m = 32; m >= 1; m >>= 1) s += __shfl_xor(s, m, 64);
  if (lane == 0) halfc2[row] = 0.5f * s;
}

__global__ __launch_bounds__(NT, 2) void vq_argmin_kernel(
    const float* __restrict__ x, const float* __restrict__ cb,
    const float* __restrict__ halfc2, int* __restrict__ out) {
  __shared__ float lds[2][(BM + BN) * BD];
  __shared__ float c2s[1024];
  const int tid = threadIdx.x;
  const int w   = tid >> 6;
  const int tc  = tid & 31;
  const int tr  = tid >> 5;
  const int r0  = blockIdx.x * BM;
  reinterpret_cast<float2*>(c2s)[tid] = reinterpret_cast<const float2*>(halfc2)[tid];
  const int sA  = tr & 7;
  const int sB  = tc & 7;
  const int sAB = sA ^ sB;
  const int cho = (((tid & 7) ^ w)) * 4;
  const int sub = tid >> 3;
  float bestv[8]; int besti[8];
#pragma unroll
  for (int i = 0; i < 8; ++i) { bestv[i] = -3.4e38f; besti[i] = 0; }
  auto stage = [&](int n0, int d0, int p) {
    float* dst  = &lds[p][0];
    float* dstB = dst + BM * BD;
#pragma unroll
    for (int r = 0; r < 2; ++r) {
      int t2 = r * NT + tid;
      glds16(x + (size_t)(r0 + r * 64 + sub) * 256 + d0 + cho, dst + t2 * 4);
    }
#pragma unroll
    for (int r = 0; r < 4; ++r) {
      int t2 = r * NT + tid;
      glds16(cb + (size_t)(n0 + r * 64 + sub) * 256 + d0 + cho, dstB + t2 * 4);
    }
  };
  stage(0, 0, 0);
  int t = 0;
  for (int nt = 0; nt < 4; ++nt) {
    float acc[8][8];
#pragma unroll
    for (int i = 0; i < 8; ++i)
#pragma unroll
      for (int j = 0; j < 8; ++j) acc[i][j] = 0.f;
    for (int dt = 0; dt < 8; ++dt, ++t) {
      const int p = t & 1;
      if (t < 31) {
        const int t1 = t + 1;
        stage((t1 >> 3) * BN, (t1 & 7) * BD, t1 & 1);
        asm volatile("s_waitcnt vmcnt(6)" ::: "memory");
      } else {
        asm volatile("s_waitcnt vmcnt(0)" ::: "memory");
      }
      __builtin_amdgcn_s_barrier();
      const float* pA = &lds[p][tr * 8 * BD];
      const float* pB = &lds[p][BM * BD + tc * 8 * BD];
#pragma unroll
      for (int cc = 0; cc < 8; ++cc) {
        const float* pBc = pB + ((cc ^ sAB) << 2);
        float4 a[8], b[8];
#pragma unroll
        for (int i = 0; i < 8; ++i)
          a[i] = *reinterpret_cast<const float4*>(pA + i * BD + cc * 4);
#pragma unroll
        for (int j = 0; j < 8; ++j)
          b[j] = *reinterpret_cast<const float4*>(pBc + j * BD);
#pragma unroll
        for (int i = 0; i < 8; ++i)
#pragma unroll
          for (int j = 0; j < 8; ++j) {
            acc[i][j] = fmaf(a[i].x, b[j].x, acc[i][j]);
            acc[i][j] = fmaf(a[i].y, b[j].y, acc[i][j]);
            acc[i][j] = fmaf(a[i].z, b[j].z, acc[i][j]);
            acc[i][j] = fmaf(a[i].w, b[j].w, acc[i][j]);
          }
      }
      asm volatile("s_waitcnt lgkmcnt(0)" ::: "memory");
      __builtin_amdgcn_s_barrier();
    }
    const int n0 = nt * BN;
#pragma unroll
    for (int j = 0; j < 8; ++j) {
      const int code = n0 + tc * 8 + j;
      const float hc = c2s[code];
#pragma unroll
      for (int i = 0; i < 8; ++i) {
        float s = acc[i][j] - hc;
        if (s > bestv[i]) { bestv[i] = s; besti[i] = code; }
      }
    }
  }
#pragma unroll
  for (int i = 0; i < 8; ++i) {
#pragma unroll
    for (int m = 1; m <= 16; m <<= 1) {
      float ov = __shfl_xor(bestv[i], m, 64);
      int   oi = __shfl_xor(besti[i], m, 64);
      if (ov > bestv[i] || (ov == bestv[i] && oi < besti[i])) { bestv[i] = ov; besti[i] = oi; }
    }
  }
  if (tc == 0) {
#pragma unroll
    for (int i = 0; i < 8; ++i) out[r0 + tr * 8 + i] = besti[i];
  }
}

// ==================================== launch ====================================
extern "C" void kernel_launch(void* const* d_in, const int* in_sizes, int n_in,
                              void* d_out, int out_size, void* d_ws, size_t ws_size,
                              hipStream_t stream) {
  const float* x  = (const float*)d_in[0];   // (8,4096,256) fp32
  const float* cb = (const float*)d_in[1];   // (1024,256) fp32
  int* out = (int*)d_out;                    // (8,4096) int32

  // ws layout (bytes): xh 16M | xl 16M | cbh 512K | cbl 512K | hc 4K | list 128K | count 4
  const size_t OFF_XH = 0;
  const size_t OFF_XL = OFF_XH + (size_t)32768 * 256 * 2;
  const size_t OFF_CH = OFF_XL + (size_t)32768 * 256 * 2;
  const size_t OFF_CL = OFF_CH + (size_t)1024 * 256 * 2;
  const size_t OFF_HC = OFF_CL + (size_t)1024 * 256 * 2;
  const size_t OFF_LS = OFF_HC + (size_t)1024 * 4;
  const size_t OFF_CT = OFF_LS + (size_t)32768 * 4;
  const size_t NEED   = OFF_CT + 64;

  if (ws_size >= NEED) {
    unsigned short* xh  = (unsigned short*)((char*)d_ws + OFF_XH);
    unsigned short* xl  = (unsigned short*)((char*)d_ws + OFF_XL);
    unsigned short* cbh = (unsigned short*)((char*)d_ws + OFF_CH);
    unsigned short* cbl = (unsigned short*)((char*)d_ws + OFF_CL);
    float* hc  = (float*)((char*)d_ws + OFF_HC);
    int* list  = (int*)((char*)d_ws + OFF_LS);
    int* count = (int*)((char*)d_ws + OFF_CT);

    hipLaunchKernelGGL(vq_prep_x, dim3(2048), dim3(256), 0, stream, x, xh, xl, count);
    hipLaunchKernelGGL(vq_prep_cb, dim3(256), dim3(256), 0, stream, cb, cbh, cbl, hc);
    hipLaunchKernelGGL(vq_mfma_kernel, dim3(256), dim3(512), 0, stream,
                       xh, xl, cbh, cbl, hc, out, list, count);
    hipLaunchKernelGGL(vq_cleanup, dim3(256), dim3(256), 0, stream,
                       x, cb, hc, list, count, out);
  } else {
    float* c2 = (float*)d_ws;
    hipLaunchKernelGGL(vq_c2_kernel, dim3(256), dim3(256), 0, stream, cb, c2);
    hipLaunchKernelGGL(vq_argmin_kernel, dim3(32768 / BM), dim3(NT), 0, stream,
                       x, cb, c2, out);
  }
}

// Round 7
// 117.233 us; speedup vs baseline: 1.9992x; 1.2003x over previous
//
#include <hip/hip_runtime.h>
#include <stdint.h>

typedef __attribute__((ext_vector_type(8))) _Float16 f16x8;
typedef __attribute__((ext_vector_type(4))) float f32x4;

#define MARG 0.1875f

// async global->LDS, 16B per lane
__device__ __forceinline__ void glds16(const void* g, void* l) {
  __builtin_amdgcn_global_load_lds(
      (const __attribute__((address_space(1))) void*)g,
      (__attribute__((address_space(3))) void*)l, 16, 0, 0);
}

__device__ __forceinline__ unsigned short f2h(float f) {
  return __builtin_bit_cast(unsigned short, (_Float16)f);  // RN
}

// ---------------- prep x: fp32 -> fp16; also zero flag counter ----------------
__global__ __launch_bounds__(256) void vq_prep_x(const float* __restrict__ x,
                                                 unsigned short* __restrict__ xh,
                                                 int* __restrict__ count) {
  size_t base = ((size_t)blockIdx.x * 256 + threadIdx.x) * 16;
#pragma unroll
  for (int q = 0; q < 4; ++q) {
    float4 v = *reinterpret_cast<const float4*>(x + base + q * 4);
    ushort4 h;
    h.x = f2h(v.x); h.y = f2h(v.y); h.z = f2h(v.z); h.w = f2h(v.w);
    *reinterpret_cast<ushort4*>(xh + base + q * 4) = h;
  }
  if (blockIdx.x == 0 && threadIdx.x == 0) *count = 0;
}

// ---------------- prep cb: fp16 convert + hc[k] = 0.5*|c_k|^2 (fp32-exact) --------
__global__ __launch_bounds__(256) void vq_prep_cb(const float* __restrict__ cb,
                                                  unsigned short* __restrict__ cbh,
                                                  float* __restrict__ hc) {
  int w = threadIdx.x >> 6, lane = threadIdx.x & 63;
  int row = blockIdx.x * 4 + w;
  size_t off = (size_t)row * 256 + lane * 4;
  float4 v = *reinterpret_cast<const float4*>(cb + off);
  ushort4 h;
  h.x = f2h(v.x); h.y = f2h(v.y); h.z = f2h(v.z); h.w = f2h(v.w);
  *reinterpret_cast<ushort4*>(cbh + off) = h;
  float s = v.x * v.x + v.y * v.y + v.z * v.z + v.w * v.w;
#pragma unroll
  for (int m = 32; m >= 1; m >>= 1) s += __shfl_xor(s, m, 64);
  if (lane == 0) hc[row] = 0.5f * s;
}

// ---------------- main: single-product fp16 MFMA GEMM + best/second argmax --------
// 512 thr = 8 waves (2M x 4N), wave tile 64 rows x 64 cols, block 128 rows x 1024 codes
// (4 chunks of 256). BK=32 (one mfma K). LDS: dbuf (A 8K + B 16K each) = 48KB.
// Ambiguous rows (second within MARG of best) are appended to a compact list and
// exactly recomputed in fp32 by vq_cleanup -> bit-exact argmin.
__global__ __launch_bounds__(512, 2) void vq_mfma_kernel(
    const unsigned short* __restrict__ xh, const unsigned short* __restrict__ cbh,
    const float* __restrict__ hc, int* __restrict__ out,
    int* __restrict__ list, int* __restrict__ count) {
  __shared__ unsigned short sm[24576];  // 48 KB: [A(4096) x2 | B(8192) x2]
  __shared__ float c2s[1024];           // 4 KB
  __shared__ float cbv[4][128];         // cross-wave merge: best
  __shared__ int   cbi[4][128];         //   index
  __shared__ float csv[4][128];         //   second-best

  const int tid = threadIdx.x;
  const int lane = tid & 63;
  const int wave = tid >> 6;
  const int wr = wave >> 2;   // 0..1 (M)
  const int wc = wave & 3;    // 0..3 (N)
  const int l15 = lane & 15;
  const int l4  = lane >> 4;  // 0..3
  const int r0 = blockIdx.x * 128;

  reinterpret_cast<float2*>(c2s)[tid] = reinterpret_cast<const float2*>(hc)[tid];

  // staging: row = tid>>2, stored chunk = tid&3 (linear dest). Source chunk is
  // pre-swizzled by ((row>>1)&3) so reads can XOR the same way (bank spread).
  const int srow = tid >> 2;
  const int sch  = (tid & 3) ^ ((tid >> 3) & 3);

  auto stage = [&](int T1) {
    const int p = T1 & 1;
    const int n0 = (T1 >> 3) << 8;
    const int d0 = (T1 & 7) << 5;
    unsigned short* A = sm + p * 4096;
    unsigned short* B = sm + 8192 + p * 8192;
    glds16(xh + (size_t)(r0 + srow) * 256 + d0 + sch * 8, A + tid * 8);
#pragma unroll
    for (int r = 0; r < 2; ++r) {
      int idx = r * 512 + tid;
      int bch = (idx & 3) ^ ((idx >> 3) & 3);
      glds16(cbh + (size_t)(n0 + (idx >> 2)) * 256 + d0 + bch * 8, B + idx * 8);
    }
  };

  float bestv[4][4], secondv[4][4];
  int besti[4][4];
#pragma unroll
  for (int tr = 0; tr < 4; ++tr)
#pragma unroll
    for (int g = 0; g < 4; ++g) {
      bestv[tr][g] = -3.4e38f; secondv[tr][g] = -3.4e38f; besti[tr][g] = 0;
    }

  stage(0);  // prologue: 3 glds in flight

  const int swzf = (l15 >> 1) & 3;  // read-side chunk XOR ((row>>1)&3 == (l15>>1)&3)

  int T = 0;
  for (int nt = 0; nt < 4; ++nt) {
    f32x4 acc[4][4];
#pragma unroll
    for (int tr = 0; tr < 4; ++tr)
#pragma unroll
      for (int tc = 0; tc < 4; ++tc) acc[tr][tc] = (f32x4){0.f, 0.f, 0.f, 0.f};

    for (int dt = 0; dt < 8; ++dt, ++T) {
      const int p = T & 1;
      if (T < 31) {
        stage(T + 1);
        // 3 newest (next stage) stay in flight; stage T's 3 are complete.
        asm volatile("s_waitcnt vmcnt(3)" ::: "memory");
      } else {
        asm volatile("s_waitcnt vmcnt(0)" ::: "memory");
      }
      __builtin_amdgcn_s_barrier();

      const unsigned short* A = sm + p * 4096;
      const unsigned short* B = sm + 8192 + p * 8192;

      f16x8 af[4], bf[4];
#pragma unroll
      for (int tr = 0; tr < 4; ++tr) {
        int arow = wr * 64 + tr * 16 + l15;
        af[tr] = *reinterpret_cast<const f16x8*>(A + arow * 32 + (l4 ^ swzf) * 8);
      }
#pragma unroll
      for (int tc = 0; tc < 4; ++tc) {
        int bcol = wc * 64 + tc * 16 + l15;
        bf[tc] = *reinterpret_cast<const f16x8*>(B + bcol * 32 + (l4 ^ swzf) * 8);
      }

#pragma unroll
      for (int tr = 0; tr < 4; ++tr)
#pragma unroll
        for (int tc = 0; tc < 4; ++tc)
          acc[tr][tc] = __builtin_amdgcn_mfma_f32_16x16x32_f16(af[tr], bf[tc], acc[tr][tc], 0, 0, 0);

      asm volatile("s_waitcnt lgkmcnt(0)" ::: "memory");
      __builtin_amdgcn_s_barrier();
    }

    // fold chunk scores into running best/second (codes ascending per thread)
    const int cb0 = nt * 256 + wc * 64 + l15;
    float hcv[4];
#pragma unroll
    for (int tc = 0; tc < 4; ++tc) hcv[tc] = c2s[cb0 + tc * 16];
#pragma unroll
    for (int tr = 0; tr < 4; ++tr)
#pragma unroll
      for (int tc = 0; tc < 4; ++tc) {
        const int code = cb0 + tc * 16;
#pragma unroll
        for (int g = 0; g < 4; ++g) {
          float s = acc[tr][tc][g] - hcv[tc];
          bool gt = s > bestv[tr][g];
          float ns = gt ? bestv[tr][g] : fmaxf(secondv[tr][g], s);
          bestv[tr][g] = gt ? s : bestv[tr][g];
          besti[tr][g] = gt ? code : besti[tr][g];
          secondv[tr][g] = ns;
        }
      }
  }

  // within-wave merge across the 16 l15-lanes sharing each row-slot
#pragma unroll
  for (int tr = 0; tr < 4; ++tr)
#pragma unroll
    for (int g = 0; g < 4; ++g) {
      float bv = bestv[tr][g]; int bi = besti[tr][g]; float sv = secondv[tr][g];
#pragma unroll
      for (int m = 1; m < 16; m <<= 1) {
        float ov = __shfl_xor(bv, m, 64);
        int   oi = __shfl_xor(bi, m, 64);
        float os = __shfl_xor(sv, m, 64);
        sv = fmaxf(fmaxf(sv, os), fminf(bv, ov));
        bool gt = (ov > bv) || (ov == bv && oi < bi);
        bv = gt ? ov : bv;
        bi = gt ? oi : bi;
      }
      if (l15 == 0) {
        int rl = wr * 64 + tr * 16 + l4 * 4 + g;
        cbv[wc][rl] = bv; cbi[wc][rl] = bi; csv[wc][rl] = sv;
      }
    }

  // cross-wave merge: each of 4 wc-waves surveyed a disjoint 64-code slice per chunk
  __syncthreads();
  if (tid < 128) {
    float bv = cbv[0][tid]; int bi = cbi[0][tid]; float sv = csv[0][tid];
#pragma unroll
    for (int w2 = 1; w2 < 4; ++w2) {
      float ov = cbv[w2][tid]; int oi = cbi[w2][tid]; float os = csv[w2][tid];
      sv = fmaxf(fmaxf(sv, os), fminf(bv, ov));
      bool gt = (ov > bv) || (ov == bv && oi < bi);
      bv = gt ? ov : bv;
      bi = gt ? oi : bi;
    }
    out[r0 + tid] = bi;
    if (sv >= bv - MARG) {           // ambiguous: append to compact recheck list
      int slot = atomicAdd(count, 1);
      list[slot] = r0 + tid;
    }
  }
}

// -------- cleanup: batched exact fp32 recompute, 16 flagged rows per block --------
__global__ __launch_bounds__(256) void vq_cleanup(const float* __restrict__ x,
                                                  const float* __restrict__ cb,
                                                  const float* __restrict__ hc,
                                                  const int* __restrict__ list,
                                                  const int* __restrict__ count,
                                                  int* __restrict__ out) {
  __shared__ float xt[16][256];   // 16 KB
  __shared__ int rowids[16];
  __shared__ float wbv[4][16];
  __shared__ int   wbi[4][16];
  const int tid = threadIdx.x;
  const int n = *count;

  for (int t0 = blockIdx.x * 16; t0 < n; t0 += gridDim.x * 16) {
    __syncthreads();  // protect LDS reuse across grid-stride iterations
    if (tid < 16) rowids[tid] = (t0 + tid < n) ? list[t0 + tid] : -1;
    __syncthreads();
    {
      int j = tid >> 4, seg = tid & 15;
      int row = rowids[j];
      if (row < 0) row = rowids[0];  // dead slot: stage any valid row (result unused)
      const float4* src = reinterpret_cast<const float4*>(x + (size_t)row * 256 + seg * 16);
      float4* dst = reinterpret_cast<float4*>(&xt[j][seg * 16]);
#pragma unroll
      for (int q = 0; q < 4; ++q) dst[q] = src[q];
    }
    __syncthreads();

    float accv[4][16];
#pragma unroll
    for (int k = 0; k < 4; ++k)
#pragma unroll
      for (int j = 0; j < 16; ++j) accv[k][j] = 0.f;

#pragma unroll 2
    for (int d0 = 0; d0 < 256; d0 += 4) {
      float4 c4[4];
#pragma unroll
      for (int k = 0; k < 4; ++k)
        c4[k] = *reinterpret_cast<const float4*>(cb + (size_t)(k * 256 + tid) * 256 + d0);
#pragma unroll
      for (int j = 0; j < 16; ++j) {
        float4 xv = *reinterpret_cast<const float4*>(&xt[j][d0]);  // wave-broadcast
#pragma unroll
        for (int k = 0; k < 4; ++k) {
          accv[k][j] = fmaf(c4[k].x, xv.x, accv[k][j]);
          accv[k][j] = fmaf(c4[k].y, xv.y, accv[k][j]);
          accv[k][j] = fmaf(c4[k].z, xv.z, accv[k][j]);
          accv[k][j] = fmaf(c4[k].w, xv.w, accv[k][j]);
        }
      }
    }

    float hcv[4];
#pragma unroll
    for (int k = 0; k < 4; ++k) hcv[k] = hc[k * 256 + tid];

#pragma unroll
    for (int j = 0; j < 16; ++j) {
      float bv = accv[0][j] - hcv[0]; int bi = tid;
#pragma unroll
      for (int k = 1; k < 4; ++k) {
        float s = accv[k][j] - hcv[k];
        if (s > bv) { bv = s; bi = k * 256 + tid; }  // codes ascending in k
      }
#pragma unroll
      for (int m = 1; m < 64; m <<= 1) {
        float ov = __shfl_xor(bv, m, 64);
        int   oi = __shfl_xor(bi, m, 64);
        bool gt = (ov > bv) || (ov == bv && oi < bi);
        bv = gt ? ov : bv;
        bi = gt ? oi : bi;
      }
      if ((tid & 63) == 0) { wbv[tid >> 6][j] = bv; wbi[tid >> 6][j] = bi; }
    }
    __syncthreads();
    if (tid < 16 && rowids[tid] >= 0) {
      float bv = wbv[0][tid]; int bi = wbi[0][tid];
#pragma unroll
      for (int w2 = 1; w2 < 4; ++w2) {
        float ov = wbv[w2][tid]; int oi = wbi[w2][tid];
        if (ov > bv || (ov == bv && oi < bi)) { bv = ov; bi = oi; }
      }
      out[rowids[tid]] = bi;
    }
  }
}

// ================= fallback fp32 path (R2 kernel) if ws is too small =================
#define BM 128
#define BN 256
#define BD 32
#define NT 512

__global__ __launch_bounds__(256) void vq_c2_kernel(const float* __restrict__ cb,
                                                    float* __restrict__ halfc2) {
  int row  = blockIdx.x * 4 + (threadIdx.x >> 6);
  int lane = threadIdx.x & 63;
  float4 v = *reinterpret_cast<const float4*>(cb + (size_t)row * 256 + lane * 4);
  float s = v.x * v.x + v.y * v.y + v.z * v.z + v.w * v.w;
#pragma unroll
  for (int m = 32; m >= 1; m >>= 1) s += __shfl_xor(s, m, 64);
  if (lane == 0) halfc2[row] = 0.5f * s;
}

__global__ __launch_bounds__(NT, 2) void vq_argmin_kernel(
    const float* __restrict__ x, const float* __restrict__ cb,
    const float* __restrict__ halfc2, int* __restrict__ out) {
  __shared__ float lds[2][(BM + BN) * BD];
  __shared__ float c2s[1024];
  const int tid = threadIdx.x;
  const int w   = tid >> 6;
  const int tc  = tid & 31;
  const int tr  = tid >> 5;
  const int r0  = blockIdx.x * BM;
  reinterpret_cast<float2*>(c2s)[tid] = reinterpret_cast<const float2*>(halfc2)[tid];
  const int sA  = tr & 7;
  const int sB  = tc & 7;
  const int sAB = sA ^ sB;
  const int cho = (((tid & 7) ^ w)) * 4;
  const int sub = tid >> 3;
  float bestv[8]; int besti[8];
#pragma unroll
  for (int i = 0; i < 8; ++i) { bestv[i] = -3.4e38f; besti[i] = 0; }
  auto stage = [&](int n0, int d0, int p) {
    float* dst  = &lds[p][0];
    float* dstB = dst + BM * BD;
#pragma unroll
    for (int r = 0; r < 2; ++r) {
      int t2 = r * NT + tid;
      glds16(x + (size_t)(r0 + r * 64 + sub) * 256 + d0 + cho, dst + t2 * 4);
    }
#pragma unroll
    for (int r = 0; r < 4; ++r) {
      int t2 = r * NT + tid;
      glds16(cb + (size_t)(n0 + r * 64 + sub) * 256 + d0 + cho, dstB + t2 * 4);
    }
  };
  stage(0, 0, 0);
  int t = 0;
  for (int nt = 0; nt < 4; ++nt) {
    float acc[8][8];
#pragma unroll
    for (int i = 0; i < 8; ++i)
#pragma unroll
      for (int j = 0; j < 8; ++j) acc[i][j] = 0.f;
    for (int dt = 0; dt < 8; ++dt, ++t) {
      const int p = t & 1;
      if (t < 31) {
        const int t1 = t + 1;
        stage((t1 >> 3) * BN, (t1 & 7) * BD, t1 & 1);
        asm volatile("s_waitcnt vmcnt(6)" ::: "memory");
      } else {
        asm volatile("s_waitcnt vmcnt(0)" ::: "memory");
      }
      __builtin_amdgcn_s_barrier();
      const float* pA = &lds[p][tr * 8 * BD];
      const float* pB = &lds[p][BM * BD + tc * 8 * BD];
#pragma unroll
      for (int cc = 0; cc < 8; ++cc) {
        const float* pBc = pB + ((cc ^ sAB) << 2);
        float4 a[8], b[8];
#pragma unroll
        for (int i = 0; i < 8; ++i)
          a[i] = *reinterpret_cast<const float4*>(pA + i * BD + cc * 4);
#pragma unroll
        for (int j = 0; j < 8; ++j)
          b[j] = *reinterpret_cast<const float4*>(pBc + j * BD);
#pragma unroll
        for (int i = 0; i < 8; ++i)
#pragma unroll
          for (int j = 0; j < 8; ++j) {
            acc[i][j] = fmaf(a[i].x, b[j].x, acc[i][j]);
            acc[i][j] = fmaf(a[i].y, b[j].y, acc[i][j]);
            acc[i][j] = fmaf(a[i].z, b[j].z, acc[i][j]);
            acc[i][j] = fmaf(a[i].w, b[j].w, acc[i][j]);
          }
      }
      asm volatile("s_waitcnt lgkmcnt(0)" ::: "memory");
      __builtin_amdgcn_s_barrier();
    }
    const int n0 = nt * BN;
#pragma unroll
    for (int j = 0; j < 8; ++j) {
      const int code = n0 + tc * 8 + j;
      const float hc = c2s[code];
#pragma unroll
      for (int i = 0; i < 8; ++i) {
        float s = acc[i][j] - hc;
        if (s > bestv[i]) { bestv[i] = s; besti[i] = code; }
      }
    }
  }
#pragma unroll
  for (int i = 0; i < 8; ++i) {
#pragma unroll
    for (int m = 1; m <= 16; m <<= 1) {
      float ov = __shfl_xor(bestv[i], m, 64);
      int   oi = __shfl_xor(besti[i], m, 64);
      if (ov > bestv[i] || (ov == bestv[i] && oi < besti[i])) { bestv[i] = ov; besti[i] = oi; }
    }
  }
  if (tc == 0) {
#pragma unroll
    for (int i = 0; i < 8; ++i) out[r0 + tr * 8 + i] = besti[i];
  }
}

// ==================================== launch ====================================
extern "C" void kernel_launch(void* const* d_in, const int* in_sizes, int n_in,
                              void* d_out, int out_size, void* d_ws, size_t ws_size,
                              hipStream_t stream) {
  const float* x  = (const float*)d_in[0];   // (8,4096,256) fp32
  const float* cb = (const float*)d_in[1];   // (1024,256) fp32
  int* out = (int*)d_out;                    // (8,4096) int32

  // ws layout (bytes): xh 16M | cbh 512K | hc 4K | list 128K | count 4
  const size_t OFF_XH = 0;
  const size_t OFF_CH = OFF_XH + (size_t)32768 * 256 * 2;
  const size_t OFF_HC = OFF_CH + (size_t)1024 * 256 * 2;
  const size_t OFF_LS = OFF_HC + (size_t)1024 * 4;
  const size_t OFF_CT = OFF_LS + (size_t)32768 * 4;
  const size_t NEED   = OFF_CT + 64;

  if (ws_size >= NEED) {
    unsigned short* xh  = (unsigned short*)((char*)d_ws + OFF_XH);
    unsigned short* cbh = (unsigned short*)((char*)d_ws + OFF_CH);
    float* hc  = (float*)((char*)d_ws + OFF_HC);
    int* list  = (int*)((char*)d_ws + OFF_LS);
    int* count = (int*)((char*)d_ws + OFF_CT);

    hipLaunchKernelGGL(vq_prep_x, dim3(2048), dim3(256), 0, stream, x, xh, count);
    hipLaunchKernelGGL(vq_prep_cb, dim3(256), dim3(256), 0, stream, cb, cbh, hc);
    hipLaunchKernelGGL(vq_mfma_kernel, dim3(256), dim3(512), 0, stream,
                       xh, cbh, hc, out, list, count);
    hipLaunchKernelGGL(vq_cleanup, dim3(256), dim3(256), 0, stream,
                       x, cb, hc, list, count, out);
  } else {
    float* c2 = (float*)d_ws;
    hipLaunchKernelGGL(vq_c2_kernel, dim3(256), dim3(256), 0, stream, cb, c2);
    hipLaunchKernelGGL(vq_argmin_kernel, dim3(32768 / BM), dim3(NT), 0, stream,
                       x, cb, c2, out);
  }
}

// Round 8
// 95.986 us; speedup vs baseline: 2.4418x; 1.2214x over previous
//
#include <hip/hip_runtime.h>
#include <stdint.h>

typedef __attribute__((ext_vector_type(8))) _Float16 f16x8;
typedef __attribute__((ext_vector_type(4))) float f32x4;

#define MARG 0.1875f

// async global->LDS, 16B per lane
__device__ __forceinline__ void glds16(const void* g, void* l) {
  __builtin_amdgcn_global_load_lds(
      (const __attribute__((address_space(1))) void*)g,
      (__attribute__((address_space(3))) void*)l, 16, 0, 0);
}

__device__ __forceinline__ unsigned short f2h(float f) {
  return __builtin_bit_cast(unsigned short, (_Float16)f);  // RN
}

// ---------------- prep x: fp32 -> fp16; also zero flag counter ----------------
__global__ __launch_bounds__(256) void vq_prep_x(const float* __restrict__ x,
                                                 unsigned short* __restrict__ xh,
                                                 int* __restrict__ count) {
  size_t base = ((size_t)blockIdx.x * 256 + threadIdx.x) * 16;
#pragma unroll
  for (int q = 0; q < 4; ++q) {
    float4 v = *reinterpret_cast<const float4*>(x + base + q * 4);
    ushort4 h;
    h.x = f2h(v.x); h.y = f2h(v.y); h.z = f2h(v.z); h.w = f2h(v.w);
    *reinterpret_cast<ushort4*>(xh + base + q * 4) = h;
  }
  if (blockIdx.x == 0 && threadIdx.x == 0) *count = 0;
}

// ---------------- prep cb: fp16 convert + hc[k] = 0.5*|c_k|^2 (fp32-exact) --------
__global__ __launch_bounds__(256) void vq_prep_cb(const float* __restrict__ cb,
                                                  unsigned short* __restrict__ cbh,
                                                  float* __restrict__ hc) {
  int w = threadIdx.x >> 6, lane = threadIdx.x & 63;
  int row = blockIdx.x * 4 + w;
  size_t off = (size_t)row * 256 + lane * 4;
  float4 v = *reinterpret_cast<const float4*>(cb + off);
  ushort4 h;
  h.x = f2h(v.x); h.y = f2h(v.y); h.z = f2h(v.z); h.w = f2h(v.w);
  *reinterpret_cast<ushort4*>(cbh + off) = h;
  float s = v.x * v.x + v.y * v.y + v.z * v.z + v.w * v.w;
#pragma unroll
  for (int m = 32; m >= 1; m >>= 1) s += __shfl_xor(s, m, 64);
  if (lane == 0) hc[row] = 0.5f * s;
}

// ---------------- main: fp16 MFMA GEMM + best/second argmax, BM=64 ----------------
// 512 thr = 8 waves (2M x 4N), wave tile 32 rows x 64 cols, block 64 rows x 1024
// codes (4 chunks of 256). BK=32. LDS dbuf: A 4K + B 16K per phase = 40KB total
// -> ~47KB/block -> 2 blocks/CU co-resident (barrier-drain overlap across blocks).
// Ambiguous rows (second within MARG of best) go to a compact recheck list.
__global__ __launch_bounds__(512, 4) void vq_mfma_kernel(
    const unsigned short* __restrict__ xh, const unsigned short* __restrict__ cbh,
    const float* __restrict__ hc, int* __restrict__ out,
    int* __restrict__ list, int* __restrict__ count) {
  __shared__ unsigned short sm[20480];  // 40 KB: A[2][2048] | B[2][8192]
  __shared__ float c2s[1024];           // 4 KB
  __shared__ float cbv[4][64];          // cross-wave merge: best
  __shared__ int   cbi[4][64];          //   index
  __shared__ float csv[4][64];          //   second-best

  const int tid = threadIdx.x;
  const int lane = tid & 63;
  const int wave = tid >> 6;
  const int wr = wave >> 2;   // 0..1 (M)
  const int wc = wave & 3;    // 0..3 (N)
  const int l15 = lane & 15;
  const int l4  = lane >> 4;  // 0..3
  // XCD-aware swizzle: 512 blocks, 8 XCDs -> contiguous 64-block chunks per XCD
  const int bswz = (blockIdx.x & 7) * 64 + (blockIdx.x >> 3);
  const int r0 = bswz * 64;

  reinterpret_cast<float2*>(c2s)[tid] = reinterpret_cast<const float2*>(hc)[tid];

  // A staging: slot s=tid&255 (waves 0-3 and 4-7 write identical data -> uniform
  // vmcnt). row=s>>2, dest chunk=s&3 linear; source chunk pre-swizzled by (row>>1)&3.
  const int sA   = tid & 255;
  const int srow = sA >> 2;
  const int schA = (sA & 3) ^ ((sA >> 3) & 3);

  auto stage = [&](int T1) {
    const int p = T1 & 1;
    const int n0 = (T1 >> 3) << 8;
    const int d0 = (T1 & 7) << 5;
    unsigned short* A = sm + p * 2048;
    unsigned short* B = sm + 4096 + p * 8192;
    glds16(xh + (size_t)(r0 + srow) * 256 + d0 + schA * 8, A + sA * 8);
#pragma unroll
    for (int r = 0; r < 2; ++r) {
      int idx = r * 512 + tid;
      int bch = (idx & 3) ^ ((idx >> 3) & 3);
      glds16(cbh + (size_t)(n0 + (idx >> 2)) * 256 + d0 + bch * 8, B + idx * 8);
    }
  };

  float bestv[2][4], secondv[2][4];
  int besti[2][4];
#pragma unroll
  for (int tr = 0; tr < 2; ++tr)
#pragma unroll
    for (int g = 0; g < 4; ++g) {
      bestv[tr][g] = -3.4e38f; secondv[tr][g] = -3.4e38f; besti[tr][g] = 0;
    }

  stage(0);  // prologue: 3 glds in flight

  const int swzf = (l15 >> 1) & 3;  // read-side chunk XOR ((row>>1)&3 == (l15>>1)&3)

  int T = 0;
  for (int nt = 0; nt < 4; ++nt) {
    f32x4 acc[2][4];
#pragma unroll
    for (int tr = 0; tr < 2; ++tr)
#pragma unroll
      for (int tc = 0; tc < 4; ++tc) acc[tr][tc] = (f32x4){0.f, 0.f, 0.f, 0.f};

    for (int dt = 0; dt < 8; ++dt, ++T) {
      const int p = T & 1;
      if (T < 31) {
        stage(T + 1);
        // 3 newest (next stage) stay in flight; stage T's 3 are complete.
        asm volatile("s_waitcnt vmcnt(3)" ::: "memory");
      } else {
        asm volatile("s_waitcnt vmcnt(0)" ::: "memory");
      }
      __builtin_amdgcn_s_barrier();

      const unsigned short* A = sm + p * 2048;
      const unsigned short* B = sm + 4096 + p * 8192;

      f16x8 af[2], bf[4];
#pragma unroll
      for (int tr = 0; tr < 2; ++tr) {
        int arow = wr * 32 + tr * 16 + l15;
        af[tr] = *reinterpret_cast<const f16x8*>(A + arow * 32 + (l4 ^ swzf) * 8);
      }
#pragma unroll
      for (int tc = 0; tc < 4; ++tc) {
        int bcol = wc * 64 + tc * 16 + l15;
        bf[tc] = *reinterpret_cast<const f16x8*>(B + bcol * 32 + (l4 ^ swzf) * 8);
      }

#pragma unroll
      for (int tr = 0; tr < 2; ++tr)
#pragma unroll
        for (int tc = 0; tc < 4; ++tc)
          acc[tr][tc] = __builtin_amdgcn_mfma_f32_16x16x32_f16(af[tr], bf[tc], acc[tr][tc], 0, 0, 0);

      asm volatile("s_waitcnt lgkmcnt(0)" ::: "memory");
      __builtin_amdgcn_s_barrier();
    }

    // fold chunk scores into running best/second (codes ascending per thread)
    const int cb0 = nt * 256 + wc * 64 + l15;
    float hcv[4];
#pragma unroll
    for (int tc = 0; tc < 4; ++tc) hcv[tc] = c2s[cb0 + tc * 16];
#pragma unroll
    for (int tr = 0; tr < 2; ++tr)
#pragma unroll
      for (int tc = 0; tc < 4; ++tc) {
        const int code = cb0 + tc * 16;
#pragma unroll
        for (int g = 0; g < 4; ++g) {
          float s = acc[tr][tc][g] - hcv[tc];
          bool gt = s > bestv[tr][g];
          float ns = gt ? bestv[tr][g] : fmaxf(secondv[tr][g], s);
          bestv[tr][g] = gt ? s : bestv[tr][g];
          besti[tr][g] = gt ? code : besti[tr][g];
          secondv[tr][g] = ns;
        }
      }
  }

  // within-wave merge across the 16 l15-lanes sharing each row-slot
#pragma unroll
  for (int tr = 0; tr < 2; ++tr)
#pragma unroll
    for (int g = 0; g < 4; ++g) {
      float bv = bestv[tr][g]; int bi = besti[tr][g]; float sv = secondv[tr][g];
#pragma unroll
      for (int m = 1; m < 16; m <<= 1) {
        float ov = __shfl_xor(bv, m, 64);
        int   oi = __shfl_xor(bi, m, 64);
        float os = __shfl_xor(sv, m, 64);
        sv = fmaxf(fmaxf(sv, os), fminf(bv, ov));
        bool gt = (ov > bv) || (ov == bv && oi < bi);
        bv = gt ? ov : bv;
        bi = gt ? oi : bi;
      }
      if (l15 == 0) {
        int rl = wr * 32 + tr * 16 + l4 * 4 + g;
        cbv[wc][rl] = bv; cbi[wc][rl] = bi; csv[wc][rl] = sv;
      }
    }

  // cross-wave merge: each of 4 wc-waves surveyed a disjoint 64-code slice per chunk
  __syncthreads();
  if (tid < 64) {
    float bv = cbv[0][tid]; int bi = cbi[0][tid]; float sv = csv[0][tid];
#pragma unroll
    for (int w2 = 1; w2 < 4; ++w2) {
      float ov = cbv[w2][tid]; int oi = cbi[w2][tid]; float os = csv[w2][tid];
      sv = fmaxf(fmaxf(sv, os), fminf(bv, ov));
      bool gt = (ov > bv) || (ov == bv && oi < bi);
      bv = gt ? ov : bv;
      bi = gt ? oi : bi;
    }
    out[r0 + tid] = bi;
    if (sv >= bv - MARG) {           // ambiguous: append to compact recheck list
      int slot = atomicAdd(count, 1);
      list[slot] = r0 + tid;
    }
  }
}

// -------- cleanup v3: batched exact fp32 recompute, 16 rows/tile, 8 waves ---------
// 512 threads: thread owns codes {tid, tid+512} -> half the per-thread FMA of v2,
// 2 waves/SIMD hide the strided codebook gather.
__global__ __launch_bounds__(512) void vq_cleanup(const float* __restrict__ x,
                                                  const float* __restrict__ cb,
                                                  const float* __restrict__ hc,
                                                  const int* __restrict__ list,
                                                  const int* __restrict__ count,
                                                  int* __restrict__ out) {
  __shared__ float xt[16][256];   // 16 KB
  __shared__ int rowids[16];
  __shared__ float wbv[8][16];
  __shared__ int   wbi[8][16];
  const int tid = threadIdx.x;
  const int wave = tid >> 6;
  const int n = *count;

  for (int t0 = blockIdx.x * 16; t0 < n; t0 += gridDim.x * 16) {
    __syncthreads();  // protect LDS reuse across grid-stride iterations
    if (tid < 16) rowids[tid] = (t0 + tid < n) ? list[t0 + tid] : -1;
    __syncthreads();
    {
      int j = tid >> 5, seg = tid & 31;
      int row = rowids[j];
      if (row < 0) row = rowids[0];  // dead slot: stage any valid row (result unused)
      const float4* src = reinterpret_cast<const float4*>(x + (size_t)row * 256 + seg * 8);
      float4* dst = reinterpret_cast<float4*>(&xt[j][seg * 8]);
      dst[0] = src[0]; dst[1] = src[1];
    }
    __syncthreads();

    float acc0[16], acc1[16];
#pragma unroll
    for (int j = 0; j < 16; ++j) { acc0[j] = 0.f; acc1[j] = 0.f; }

    const float* c0 = cb + (size_t)tid * 256;
    const float* c1 = cb + (size_t)(512 + tid) * 256;
#pragma unroll 4
    for (int d0 = 0; d0 < 256; d0 += 4) {
      float4 ca = *reinterpret_cast<const float4*>(c0 + d0);
      float4 cbb = *reinterpret_cast<const float4*>(c1 + d0);
#pragma unroll
      for (int j = 0; j < 16; ++j) {
        float4 xv = *reinterpret_cast<const float4*>(&xt[j][d0]);  // wave-broadcast
        acc0[j] = fmaf(ca.x, xv.x, acc0[j]);
        acc0[j] = fmaf(ca.y, xv.y, acc0[j]);
        acc0[j] = fmaf(ca.z, xv.z, acc0[j]);
        acc0[j] = fmaf(ca.w, xv.w, acc0[j]);
        acc1[j] = fmaf(cbb.x, xv.x, acc1[j]);
        acc1[j] = fmaf(cbb.y, xv.y, acc1[j]);
        acc1[j] = fmaf(cbb.z, xv.z, acc1[j]);
        acc1[j] = fmaf(cbb.w, xv.w, acc1[j]);
      }
    }

    const float h0 = hc[tid];
    const float h1 = hc[512 + tid];

#pragma unroll
    for (int j = 0; j < 16; ++j) {
      float bv = acc0[j] - h0; int bi = tid;
      float s1 = acc1[j] - h1;
      if (s1 > bv) { bv = s1; bi = 512 + tid; }  // codes ascending -> strict >
#pragma unroll
      for (int m = 1; m < 64; m <<= 1) {
        float ov = __shfl_xor(bv, m, 64);
        int   oi = __shfl_xor(bi, m, 64);
        bool gt = (ov > bv) || (ov == bv && oi < bi);
        bv = gt ? ov : bv;
        bi = gt ? oi : bi;
      }
      if ((tid & 63) == 0) { wbv[wave][j] = bv; wbi[wave][j] = bi; }
    }
    __syncthreads();
    if (tid < 16 && rowids[tid] >= 0) {
      float bv = wbv[0][tid]; int bi = wbi[0][tid];
#pragma unroll
      for (int w2 = 1; w2 < 8; ++w2) {
        float ov = wbv[w2][tid]; int oi = wbi[w2][tid];
        if (ov > bv || (ov == bv && oi < bi)) { bv = ov; bi = oi; }
      }
      out[rowids[tid]] = bi;
    }
  }
}

// ================= fallback fp32 path (R2 kernel) if ws is too small =================
#define BM 128
#define BN 256
#define BD 32
#define NT 512

__global__ __launch_bounds__(256) void vq_c2_kernel(const float* __restrict__ cb,
                                                    float* __restrict__ halfc2) {
  int row  = blockIdx.x * 4 + (threadIdx.x >> 6);
  int lane = threadIdx.x & 63;
  float4 v = *reinterpret_cast<const float4*>(cb + (size_t)row * 256 + lane * 4);
  float s = v.x * v.x + v.y * v.y + v.z * v.z + v.w * v.w;
#pragma unroll
  for (int m = 32; m >= 1; m >>= 1) s += __shfl_xor(s, m, 64);
  if (lane == 0) halfc2[row] = 0.5f * s;
}

__global__ __launch_bounds__(NT, 2) void vq_argmin_kernel(
    const float* __restrict__ x, const float* __restrict__ cb,
    const float* __restrict__ halfc2, int* __restrict__ out) {
  __shared__ float lds[2][(BM + BN) * BD];
  __shared__ float c2s[1024];
  const int tid = threadIdx.x;
  const int w   = tid >> 6;
  const int tc  = tid & 31;
  const int tr  = tid >> 5;
  const int r0  = blockIdx.x * BM;
  reinterpret_cast<float2*>(c2s)[tid] = reinterpret_cast<const float2*>(halfc2)[tid];
  const int sA  = tr & 7;
  const int sB  = tc & 7;
  const int sAB = sA ^ sB;
  const int cho = (((tid & 7) ^ w)) * 4;
  const int sub = tid >> 3;
  float bestv[8]; int besti[8];
#pragma unroll
  for (int i = 0; i < 8; ++i) { bestv[i] = -3.4e38f; besti[i] = 0; }
  auto stage = [&](int n0, int d0, int p) {
    float* dst  = &lds[p][0];
    float* dstB = dst + BM * BD;
#pragma unroll
    for (int r = 0; r < 2; ++r) {
      int t2 = r * NT + tid;
      glds16(x + (size_t)(r0 + r * 64 + sub) * 256 + d0 + cho, dst + t2 * 4);
    }
#pragma unroll
    for (int r = 0; r < 4; ++r) {
      int t2 = r * NT + tid;
      glds16(cb + (size_t)(n0 + r * 64 + sub) * 256 + d0 + cho, dstB + t2 * 4);
    }
  };
  stage(0, 0, 0);
  int t = 0;
  for (int nt = 0; nt < 4; ++nt) {
    float acc[8][8];
#pragma unroll
    for (int i = 0; i < 8; ++i)
#pragma unroll
      for (int j = 0; j < 8; ++j) acc[i][j] = 0.f;
    for (int dt = 0; dt < 8; ++dt, ++t) {
      const int p = t & 1;
      if (t < 31) {
        const int t1 = t + 1;
        stage((t1 >> 3) * BN, (t1 & 7) * BD, t1 & 1);
        asm volatile("s_waitcnt vmcnt(6)" ::: "memory");
      } else {
        asm volatile("s_waitcnt vmcnt(0)" ::: "memory");
      }
      __builtin_amdgcn_s_barrier();
      const float* pA = &lds[p][tr * 8 * BD];
      const float* pB = &lds[p][BM * BD + tc * 8 * BD];
#pragma unroll
      for (int cc = 0; cc < 8; ++cc) {
        const float* pBc = pB + ((cc ^ sAB) << 2);
        float4 a[8], b[8];
#pragma unroll
        for (int i = 0; i < 8; ++i)
          a[i] = *reinterpret_cast<const float4*>(pA + i * BD + cc * 4);
#pragma unroll
        for (int j = 0; j < 8; ++j)
          b[j] = *reinterpret_cast<const float4*>(pBc + j * BD);
#pragma unroll
        for (int i = 0; i < 8; ++i)
#pragma unroll
          for (int j = 0; j < 8; ++j) {
            acc[i][j] = fmaf(a[i].x, b[j].x, acc[i][j]);
            acc[i][j] = fmaf(a[i].y, b[j].y, acc[i][j]);
            acc[i][j] = fmaf(a[i].z, b[j].z, acc[i][j]);
            acc[i][j] = fmaf(a[i].w, b[j].w, acc[i][j]);
          }
      }
      asm volatile("s_waitcnt lgkmcnt(0)" ::: "memory");
      __builtin_amdgcn_s_barrier();
    }
    const int n0 = nt * BN;
#pragma unroll
    for (int j = 0; j < 8; ++j) {
      const int code = n0 + tc * 8 + j;
      const float hc = c2s[code];
#pragma unroll
      for (int i = 0; i < 8; ++i) {
        float s = acc[i][j] - hc;
        if (s > bestv[i]) { bestv[i] = s; besti[i] = code; }
      }
    }
  }
#pragma unroll
  for (int i = 0; i < 8; ++i) {
#pragma unroll
    for (int m = 1; m <= 16; m <<= 1) {
      float ov = __shfl_xor(bestv[i], m, 64);
      int   oi = __shfl_xor(besti[i], m, 64);
      if (ov > bestv[i] || (ov == bestv[i] && oi < besti[i])) { bestv[i] = ov; besti[i] = oi; }
    }
  }
  if (tc == 0) {
#pragma unroll
    for (int i = 0; i < 8; ++i) out[r0 + tr * 8 + i] = besti[i];
  }
}

// ==================================== launch ====================================
extern "C" void kernel_launch(void* const* d_in, const int* in_sizes, int n_in,
                              void* d_out, int out_size, void* d_ws, size_t ws_size,
                              hipStream_t stream) {
  const float* x  = (const float*)d_in[0];   // (8,4096,256) fp32
  const float* cb = (const float*)d_in[1];   // (1024,256) fp32
  int* out = (int*)d_out;                    // (8,4096) int32

  // ws layout (bytes): xh 16M | cbh 512K | hc 4K | list 128K | count 4
  const size_t OFF_XH = 0;
  const size_t OFF_CH = OFF_XH + (size_t)32768 * 256 * 2;
  const size_t OFF_HC = OFF_CH + (size_t)1024 * 256 * 2;
  const size_t OFF_LS = OFF_HC + (size_t)1024 * 4;
  const size_t OFF_CT = OFF_LS + (size_t)32768 * 4;
  const size_t NEED   = OFF_CT + 64;

  if (ws_size >= NEED) {
    unsigned short* xh  = (unsigned short*)((char*)d_ws + OFF_XH);
    unsigned short* cbh = (unsigned short*)((char*)d_ws + OFF_CH);
    float* hc  = (float*)((char*)d_ws + OFF_HC);
    int* list  = (int*)((char*)d_ws + OFF_LS);
    int* count = (int*)((char*)d_ws + OFF_CT);

    hipLaunchKernelGGL(vq_prep_x, dim3(2048), dim3(256), 0, stream, x, xh, count);
    hipLaunchKernelGGL(vq_prep_cb, dim3(256), dim3(256), 0, stream, cb, cbh, hc);
    hipLaunchKernelGGL(vq_mfma_kernel, dim3(512), dim3(512), 0, stream,
                       xh, cbh, hc, out, list, count);
    hipLaunchKernelGGL(vq_cleanup, dim3(256), dim3(512), 0, stream,
                       x, cb, hc, list, count, out);
  } else {
    float* c2 = (float*)d_ws;
    hipLaunchKernelGGL(vq_c2_kernel, dim3(256), dim3(256), 0, stream, cb, c2);
    hipLaunchKernelGGL(vq_argmin_kernel, dim3(32768 / BM), dim3(NT), 0, stream,
                       x, cb, c2, out);
  }
}

// Round 9
// 83.964 us; speedup vs baseline: 2.7914x; 1.1432x over previous
//
#include <hip/hip_runtime.h>
#include <stdint.h>

typedef __attribute__((ext_vector_type(8))) _Float16 f16x8;
typedef __attribute__((ext_vector_type(4))) float f32x4;

#define MARG 0.09375f

// async global->LDS, 16B per lane
__device__ __forceinline__ void glds16(const void* g, void* l) {
  __builtin_amdgcn_global_load_lds(
      (const __attribute__((address_space(1))) void*)g,
      (__attribute__((address_space(3))) void*)l, 16, 0, 0);
}

__device__ __forceinline__ unsigned short f2h(float f) {
  return __builtin_bit_cast(unsigned short, (_Float16)f);  // RN
}

// ---------------- prep x: fp32 -> fp16; also zero flag counter ----------------
__global__ __launch_bounds__(256) void vq_prep_x(const float* __restrict__ x,
                                                 unsigned short* __restrict__ xh,
                                                 int* __restrict__ count) {
  size_t base = ((size_t)blockIdx.x * 256 + threadIdx.x) * 16;
#pragma unroll
  for (int q = 0; q < 4; ++q) {
    float4 v = *reinterpret_cast<const float4*>(x + base + q * 4);
    ushort4 h;
    h.x = f2h(v.x); h.y = f2h(v.y); h.z = f2h(v.z); h.w = f2h(v.w);
    *reinterpret_cast<ushort4*>(xh + base + q * 4) = h;
  }
  if (blockIdx.x == 0 && threadIdx.x == 0) *count = 0;
}

// ---------------- prep cb: fp16 convert + hc[k] = 0.5*|c_k|^2 (fp32-exact) --------
__global__ __launch_bounds__(256) void vq_prep_cb(const float* __restrict__ cb,
                                                  unsigned short* __restrict__ cbh,
                                                  float* __restrict__ hc) {
  int w = threadIdx.x >> 6, lane = threadIdx.x & 63;
  int row = blockIdx.x * 4 + w;
  size_t off = (size_t)row * 256 + lane * 4;
  float4 v = *reinterpret_cast<const float4*>(cb + off);
  ushort4 h;
  h.x = f2h(v.x); h.y = f2h(v.y); h.z = f2h(v.z); h.w = f2h(v.w);
  *reinterpret_cast<ushort4*>(cbh + off) = h;
  float s = v.x * v.x + v.y * v.y + v.z * v.z + v.w * v.w;
#pragma unroll
  for (int m = 32; m >= 1; m >>= 1) s += __shfl_xor(s, m, 64);
  if (lane == 0) hc[row] = 0.5f * s;
}

// ---------------- main: fp16 MFMA GEMM + best/second argmax, BM=64 ----------------
// 512 thr = 8 waves (2M x 4N), wave tile 32 rows x 64 cols, block 64 rows x 1024
// codes (4 chunks of 256). BK=32. LDS dbuf: A 4K + B 16K per phase = 40KB total
// -> ~47KB/block -> 2 blocks/CU co-resident (barrier-drain overlap across blocks).
// Ambiguous rows (second within MARG of best) go to a compact recheck list.
__global__ __launch_bounds__(512, 4) void vq_mfma_kernel(
    const unsigned short* __restrict__ xh, const unsigned short* __restrict__ cbh,
    const float* __restrict__ hc, int* __restrict__ out,
    int* __restrict__ list, int* __restrict__ count) {
  __shared__ unsigned short sm[20480];  // 40 KB: A[2][2048] | B[2][8192]
  __shared__ float c2s[1024];           // 4 KB
  __shared__ float cbv[4][64];          // cross-wave merge: best
  __shared__ int   cbi[4][64];          //   index
  __shared__ float csv[4][64];          //   second-best

  const int tid = threadIdx.x;
  const int lane = tid & 63;
  const int wave = tid >> 6;
  const int wr = wave >> 2;   // 0..1 (M)
  const int wc = wave & 3;    // 0..3 (N)
  const int l15 = lane & 15;
  const int l4  = lane >> 4;  // 0..3
  // XCD-aware swizzle: 512 blocks, 8 XCDs -> contiguous 64-block chunks per XCD
  const int bswz = (blockIdx.x & 7) * 64 + (blockIdx.x >> 3);
  const int r0 = bswz * 64;

  reinterpret_cast<float2*>(c2s)[tid] = reinterpret_cast<const float2*>(hc)[tid];

  // A staging: slot s=tid&255 (waves 0-3 and 4-7 write identical data -> uniform
  // vmcnt). row=s>>2, dest chunk=s&3 linear; source chunk pre-swizzled by (row>>1)&3.
  const int sA   = tid & 255;
  const int srow = sA >> 2;
  const int schA = (sA & 3) ^ ((sA >> 3) & 3);

  auto stage = [&](int T1) {
    const int p = T1 & 1;
    const int n0 = (T1 >> 3) << 8;
    const int d0 = (T1 & 7) << 5;
    unsigned short* A = sm + p * 2048;
    unsigned short* B = sm + 4096 + p * 8192;
    glds16(xh + (size_t)(r0 + srow) * 256 + d0 + schA * 8, A + sA * 8);
#pragma unroll
    for (int r = 0; r < 2; ++r) {
      int idx = r * 512 + tid;
      int bch = (idx & 3) ^ ((idx >> 3) & 3);
      glds16(cbh + (size_t)(n0 + (idx >> 2)) * 256 + d0 + bch * 8, B + idx * 8);
    }
  };

  float bestv[2][4], secondv[2][4];
  int besti[2][4];
#pragma unroll
  for (int tr = 0; tr < 2; ++tr)
#pragma unroll
    for (int g = 0; g < 4; ++g) {
      bestv[tr][g] = -3.4e38f; secondv[tr][g] = -3.4e38f; besti[tr][g] = 0;
    }

  stage(0);  // prologue: 3 glds in flight

  const int swzf = (l15 >> 1) & 3;  // read-side chunk XOR ((row>>1)&3 == (l15>>1)&3)

  int T = 0;
  for (int nt = 0; nt < 4; ++nt) {
    f32x4 acc[2][4];
#pragma unroll
    for (int tr = 0; tr < 2; ++tr)
#pragma unroll
      for (int tc = 0; tc < 4; ++tc) acc[tr][tc] = (f32x4){0.f, 0.f, 0.f, 0.f};

    for (int dt = 0; dt < 8; ++dt, ++T) {
      const int p = T & 1;
      if (T < 31) {
        stage(T + 1);
        // 3 newest (next stage) stay in flight; stage T's 3 are complete.
        asm volatile("s_waitcnt vmcnt(3)" ::: "memory");
      } else {
        asm volatile("s_waitcnt vmcnt(0)" ::: "memory");
      }
      __builtin_amdgcn_s_barrier();

      const unsigned short* A = sm + p * 2048;
      const unsigned short* B = sm + 4096 + p * 8192;

      f16x8 af[2], bf[4];
#pragma unroll
      for (int tr = 0; tr < 2; ++tr) {
        int arow = wr * 32 + tr * 16 + l15;
        af[tr] = *reinterpret_cast<const f16x8*>(A + arow * 32 + (l4 ^ swzf) * 8);
      }
#pragma unroll
      for (int tc = 0; tc < 4; ++tc) {
        int bcol = wc * 64 + tc * 16 + l15;
        bf[tc] = *reinterpret_cast<const f16x8*>(B + bcol * 32 + (l4 ^ swzf) * 8);
      }

#pragma unroll
      for (int tr = 0; tr < 2; ++tr)
#pragma unroll
        for (int tc = 0; tc < 4; ++tc)
          acc[tr][tc] = __builtin_amdgcn_mfma_f32_16x16x32_f16(af[tr], bf[tc], acc[tr][tc], 0, 0, 0);

      asm volatile("s_waitcnt lgkmcnt(0)" ::: "memory");
      __builtin_amdgcn_s_barrier();
    }

    // fold chunk scores into running best/second (codes ascending per thread)
    const int cb0 = nt * 256 + wc * 64 + l15;
    float hcv[4];
#pragma unroll
    for (int tc = 0; tc < 4; ++tc) hcv[tc] = c2s[cb0 + tc * 16];
#pragma unroll
    for (int tr = 0; tr < 2; ++tr)
#pragma unroll
      for (int tc = 0; tc < 4; ++tc) {
        const int code = cb0 + tc * 16;
#pragma unroll
        for (int g = 0; g < 4; ++g) {
          float s = acc[tr][tc][g] - hcv[tc];
          bool gt = s > bestv[tr][g];
          float ns = gt ? bestv[tr][g] : fmaxf(secondv[tr][g], s);
          bestv[tr][g] = gt ? s : bestv[tr][g];
          besti[tr][g] = gt ? code : besti[tr][g];
          secondv[tr][g] = ns;
        }
      }
  }

  // within-wave merge across the 16 l15-lanes sharing each row-slot
#pragma unroll
  for (int tr = 0; tr < 2; ++tr)
#pragma unroll
    for (int g = 0; g < 4; ++g) {
      float bv = bestv[tr][g]; int bi = besti[tr][g]; float sv = secondv[tr][g];
#pragma unroll
      for (int m = 1; m < 16; m <<= 1) {
        float ov = __shfl_xor(bv, m, 64);
        int   oi = __shfl_xor(bi, m, 64);
        float os = __shfl_xor(sv, m, 64);
        sv = fmaxf(fmaxf(sv, os), fminf(bv, ov));
        bool gt = (ov > bv) || (ov == bv && oi < bi);
        bv = gt ? ov : bv;
        bi = gt ? oi : bi;
      }
      if (l15 == 0) {
        int rl = wr * 32 + tr * 16 + l4 * 4 + g;
        cbv[wc][rl] = bv; cbi[wc][rl] = bi; csv[wc][rl] = sv;
      }
    }

  // cross-wave merge: each of 4 wc-waves surveyed a disjoint 64-code slice per chunk
  __syncthreads();
  if (tid < 64) {
    float bv = cbv[0][tid]; int bi = cbi[0][tid]; float sv = csv[0][tid];
#pragma unroll
    for (int w2 = 1; w2 < 4; ++w2) {
      float ov = cbv[w2][tid]; int oi = cbi[w2][tid]; float os = csv[w2][tid];
      sv = fmaxf(fmaxf(sv, os), fminf(bv, ov));
      bool gt = (ov > bv) || (ov == bv && oi < bi);
      bv = gt ? ov : bv;
      bi = gt ? oi : bi;
    }
    out[r0 + tid] = bi;
    if (sv >= bv - MARG) {           // ambiguous: append to compact recheck list
      int slot = atomicAdd(count, 1);
      list[slot] = r0 + tid;
    }
  }
}

// -------- cleanup v4: exact fp32 recompute, 4 rows/unit -> ~3.4us unit floor ------
// 512 threads (8 waves), thread owns codes {tid, tid+512}; 4-row LDS tile (4KB).
// ~180 units at MARG=0.09375 -> single parallel round across CUs.
__global__ __launch_bounds__(512) void vq_cleanup(const float* __restrict__ x,
                                                  const float* __restrict__ cb,
                                                  const float* __restrict__ hc,
                                                  const int* __restrict__ list,
                                                  const int* __restrict__ count,
                                                  int* __restrict__ out) {
  __shared__ float xt[4][256];    // 4 KB
  __shared__ int rowids[4];
  __shared__ float wbv[8][4];
  __shared__ int   wbi[8][4];
  const int tid = threadIdx.x;
  const int wave = tid >> 6;
  const int n = *count;

  for (int t0 = blockIdx.x * 4; t0 < n; t0 += gridDim.x * 4) {
    __syncthreads();  // protect LDS reuse across grid-stride iterations
    if (tid < 4) rowids[tid] = (t0 + tid < n) ? list[t0 + tid] : -1;
    __syncthreads();
    {
      int j = tid >> 7, seg = tid & 127;
      int row = rowids[j];
      if (row < 0) row = rowids[0];  // dead slot: stage any valid row (result unused)
      *reinterpret_cast<float2*>(&xt[j][seg * 2]) =
          *reinterpret_cast<const float2*>(x + (size_t)row * 256 + seg * 2);
    }
    __syncthreads();

    float acc0[4], acc1[4];
#pragma unroll
    for (int j = 0; j < 4; ++j) { acc0[j] = 0.f; acc1[j] = 0.f; }

    const float* c0 = cb + (size_t)tid * 256;
    const float* c1 = cb + (size_t)(512 + tid) * 256;
#pragma unroll 4
    for (int d0 = 0; d0 < 256; d0 += 4) {
      float4 ca = *reinterpret_cast<const float4*>(c0 + d0);
      float4 cd = *reinterpret_cast<const float4*>(c1 + d0);
#pragma unroll
      for (int j = 0; j < 4; ++j) {
        float4 xv = *reinterpret_cast<const float4*>(&xt[j][d0]);  // wave-broadcast
        acc0[j] = fmaf(ca.x, xv.x, acc0[j]);
        acc0[j] = fmaf(ca.y, xv.y, acc0[j]);
        acc0[j] = fmaf(ca.z, xv.z, acc0[j]);
        acc0[j] = fmaf(ca.w, xv.w, acc0[j]);
        acc1[j] = fmaf(cd.x, xv.x, acc1[j]);
        acc1[j] = fmaf(cd.y, xv.y, acc1[j]);
        acc1[j] = fmaf(cd.z, xv.z, acc1[j]);
        acc1[j] = fmaf(cd.w, xv.w, acc1[j]);
      }
    }

    const float h0 = hc[tid];
    const float h1 = hc[512 + tid];

#pragma unroll
    for (int j = 0; j < 4; ++j) {
      float bv = acc0[j] - h0; int bi = tid;
      float s1 = acc1[j] - h1;
      if (s1 > bv) { bv = s1; bi = 512 + tid; }  // codes ascending -> strict >
#pragma unroll
      for (int m = 1; m < 64; m <<= 1) {
        float ov = __shfl_xor(bv, m, 64);
        int   oi = __shfl_xor(bi, m, 64);
        bool gt = (ov > bv) || (ov == bv && oi < bi);
        bv = gt ? ov : bv;
        bi = gt ? oi : bi;
      }
      if ((tid & 63) == 0) { wbv[wave][j] = bv; wbi[wave][j] = bi; }
    }
    __syncthreads();
    if (tid < 4 && rowids[tid] >= 0) {
      float bv = wbv[0][tid]; int bi = wbi[0][tid];
#pragma unroll
      for (int w2 = 1; w2 < 8; ++w2) {
        float ov = wbv[w2][tid]; int oi = wbi[w2][tid];
        if (ov > bv || (ov == bv && oi < bi)) { bv = ov; bi = oi; }
      }
      out[rowids[tid]] = bi;
    }
  }
}

// ================= fallback fp32 path (R2 kernel) if ws is too small =================
#define BM 128
#define BN 256
#define BD 32
#define NT 512

__global__ __launch_bounds__(256) void vq_c2_kernel(const float* __restrict__ cb,
                                                    float* __restrict__ halfc2) {
  int row  = blockIdx.x * 4 + (threadIdx.x >> 6);
  int lane = threadIdx.x & 63;
  float4 v = *reinterpret_cast<const float4*>(cb + (size_t)row * 256 + lane * 4);
  float s = v.x * v.x + v.y * v.y + v.z * v.z + v.w * v.w;
#pragma unroll
  for (int m = 32; m >= 1; m >>= 1) s += __shfl_xor(s, m, 64);
  if (lane == 0) halfc2[row] = 0.5f * s;
}

__global__ __launch_bounds__(NT, 2) void vq_argmin_kernel(
    const float* __restrict__ x, const float* __restrict__ cb,
    const float* __restrict__ halfc2, int* __restrict__ out) {
  __shared__ float lds[2][(BM + BN) * BD];
  __shared__ float c2s[1024];
  const int tid = threadIdx.x;
  const int w   = tid >> 6;
  const int tc  = tid & 31;
  const int tr  = tid >> 5;
  const int r0  = blockIdx.x * BM;
  reinterpret_cast<float2*>(c2s)[tid] = reinterpret_cast<const float2*>(halfc2)[tid];
  const int sA  = tr & 7;
  const int sB  = tc & 7;
  const int sAB = sA ^ sB;
  const int cho = (((tid & 7) ^ w)) * 4;
  const int sub = tid >> 3;
  float bestv[8]; int besti[8];
#pragma unroll
  for (int i = 0; i < 8; ++i) { bestv[i] = -3.4e38f; besti[i] = 0; }
  auto stage = [&](int n0, int d0, int p) {
    float* dst  = &lds[p][0];
    float* dstB = dst + BM * BD;
#pragma unroll
    for (int r = 0; r < 2; ++r) {
      int t2 = r * NT + tid;
      glds16(x + (size_t)(r0 + r * 64 + sub) * 256 + d0 + cho, dst + t2 * 4);
    }
#pragma unroll
    for (int r = 0; r < 4; ++r) {
      int t2 = r * NT + tid;
      glds16(cb + (size_t)(n0 + r * 64 + sub) * 256 + d0 + cho, dstB + t2 * 4);
    }
  };
  stage(0, 0, 0);
  int t = 0;
  for (int nt = 0; nt < 4; ++nt) {
    float acc[8][8];
#pragma unroll
    for (int i = 0; i < 8; ++i)
#pragma unroll
      for (int j = 0; j < 8; ++j) acc[i][j] = 0.f;
    for (int dt = 0; dt < 8; ++dt, ++t) {
      const int p = t & 1;
      if (t < 31) {
        const int t1 = t + 1;
        stage((t1 >> 3) * BN, (t1 & 7) * BD, t1 & 1);
        asm volatile("s_waitcnt vmcnt(6)" ::: "memory");
      } else {
        asm volatile("s_waitcnt vmcnt(0)" ::: "memory");
      }
      __builtin_amdgcn_s_barrier();
      const float* pA = &lds[p][tr * 8 * BD];
      const float* pB = &lds[p][BM * BD + tc * 8 * BD];
#pragma unroll
      for (int cc = 0; cc < 8; ++cc) {
        const float* pBc = pB + ((cc ^ sAB) << 2);
        float4 a[8], b[8];
#pragma unroll
        for (int i = 0; i < 8; ++i)
          a[i] = *reinterpret_cast<const float4*>(pA + i * BD + cc * 4);
#pragma unroll
        for (int j = 0; j < 8; ++j)
          b[j] = *reinterpret_cast<const float4*>(pBc + j * BD);
#pragma unroll
        for (int i = 0; i < 8; ++i)
#pragma unroll
          for (int j = 0; j < 8; ++j) {
            acc[i][j] = fmaf(a[i].x, b[j].x, acc[i][j]);
            acc[i][j] = fmaf(a[i].y, b[j].y, acc[i][j]);
            acc[i][j] = fmaf(a[i].z, b[j].z, acc[i][j]);
            acc[i][j] = fmaf(a[i].w, b[j].w, acc[i][j]);
          }
      }
      asm volatile("s_waitcnt lgkmcnt(0)" ::: "memory");
      __builtin_amdgcn_s_barrier();
    }
    const int n0 = nt * BN;
#pragma unroll
    for (int j = 0; j < 8; ++j) {
      const int code = n0 + tc * 8 + j;
      const float hc = c2s[code];
#pragma unroll
      for (int i = 0; i < 8; ++i) {
        float s = acc[i][j] - hc;
        if (s > bestv[i]) { bestv[i] = s; besti[i] = code; }
      }
    }
  }
#pragma unroll
  for (int i = 0; i < 8; ++i) {
#pragma unroll
    for (int m = 1; m <= 16; m <<= 1) {
      float ov = __shfl_xor(bestv[i], m, 64);
      int   oi = __shfl_xor(besti[i], m, 64);
      if (ov > bestv[i] || (ov == bestv[i] && oi < besti[i])) { bestv[i] = ov; besti[i] = oi; }
    }
  }
  if (tc == 0) {
#pragma unroll
    for (int i = 0; i < 8; ++i) out[r0 + tr * 8 + i] = besti[i];
  }
}

// ==================================== launch ====================================
extern "C" void kernel_launch(void* const* d_in, const int* in_sizes, int n_in,
                              void* d_out, int out_size, void* d_ws, size_t ws_size,
                              hipStream_t stream) {
  const float* x  = (const float*)d_in[0];   // (8,4096,256) fp32
  const float* cb = (const float*)d_in[1];   // (1024,256) fp32
  int* out = (int*)d_out;                    // (8,4096) int32

  // ws layout (bytes): xh 16M | cbh 512K | hc 4K | list 128K | count 4
  const size_t OFF_XH = 0;
  const size_t OFF_CH = OFF_XH + (size_t)32768 * 256 * 2;
  const size_t OFF_HC = OFF_CH + (size_t)1024 * 256 * 2;
  const size_t OFF_LS = OFF_HC + (size_t)1024 * 4;
  const size_t OFF_CT = OFF_LS + (size_t)32768 * 4;
  const size_t NEED   = OFF_CT + 64;

  if (ws_size >= NEED) {
    unsigned short* xh  = (unsigned short*)((char*)d_ws + OFF_XH);
    unsigned short* cbh = (unsigned short*)((char*)d_ws + OFF_CH);
    float* hc  = (float*)((char*)d_ws + OFF_HC);
    int* list  = (int*)((char*)d_ws + OFF_LS);
    int* count = (int*)((char*)d_ws + OFF_CT);

    hipLaunchKernelGGL(vq_prep_x, dim3(2048), dim3(256), 0, stream, x, xh, count);
    hipLaunchKernelGGL(vq_prep_cb, dim3(256), dim3(256), 0, stream, cb, cbh, hc);
    hipLaunchKernelGGL(vq_mfma_kernel, dim3(512), dim3(512), 0, stream,
                       xh, cbh, hc, out, list, count);
    hipLaunchKernelGGL(vq_cleanup, dim3(512), dim3(512), 0, stream,
                       x, cb, hc, list, count, out);
  } else {
    float* c2 = (float*)d_ws;
    hipLaunchKernelGGL(vq_c2_kernel, dim3(256), dim3(256), 0, stream, cb, c2);
    hipLaunchKernelGGL(vq_argmin_kernel, dim3(32768 / BM), dim3(NT), 0, stream,
                       x, cb, c2, out);
  }
}

// Round 10
// 75.875 us; speedup vs baseline: 3.0890x; 1.1066x over previous
//
#include <hip/hip_runtime.h>
#include <stdint.h>

typedef __attribute__((ext_vector_type(8))) _Float16 f16x8;
typedef __attribute__((ext_vector_type(4))) float f32x4;

#define MARG 0.09375f

// async global->LDS, 16B per lane
__device__ __forceinline__ void glds16(const void* g, void* l) {
  __builtin_amdgcn_global_load_lds(
      (const __attribute__((address_space(1))) void*)g,
      (__attribute__((address_space(3))) void*)l, 16, 0, 0);
}

__device__ __forceinline__ unsigned short f2h(float f) {
  return __builtin_bit_cast(unsigned short, (_Float16)f);  // RN
}

// ---------------- prep cb: fp16 convert + hc[k] = 0.5*|c_k|^2; zero counter -------
__global__ __launch_bounds__(256) void vq_prep_cb(const float* __restrict__ cb,
                                                  unsigned short* __restrict__ cbh,
                                                  float* __restrict__ hc,
                                                  int* __restrict__ count) {
  int w = threadIdx.x >> 6, lane = threadIdx.x & 63;
  int row = blockIdx.x * 4 + w;
  size_t off = (size_t)row * 256 + lane * 4;
  float4 v = *reinterpret_cast<const float4*>(cb + off);
  ushort4 h;
  h.x = f2h(v.x); h.y = f2h(v.y); h.z = f2h(v.z); h.w = f2h(v.w);
  *reinterpret_cast<ushort4*>(cbh + off) = h;
  float s = v.x * v.x + v.y * v.y + v.z * v.z + v.w * v.w;
#pragma unroll
  for (int m = 32; m >= 1; m >>= 1) s += __shfl_xor(s, m, 64);
  if (lane == 0) hc[row] = 0.5f * s;
  if (blockIdx.x == 0 && threadIdx.x == 0) *count = 0;
}

// ------- main (fused x-convert): fp16 MFMA GEMM + best/second argmax, BM=64 -------
// 512 thr = 8 waves (2M x 4N), wave tile 32 rows x 64 cols, block 64 rows x 1024
// codes (4 chunks of 256). Phase 0: load block's A rows fp32 -> cvt fp16 -> A_lds
// (32KB, single-buffered, XOR-swizzled byte^=(row&7)<<4 on BOTH write and read).
// K-loop stages only B (double-buffered 2x16KB, vmcnt(2)). ~71KB LDS -> 2 blk/CU.
__global__ __launch_bounds__(512, 4) void vq_mfma_kernel(
    const float* __restrict__ x, const unsigned short* __restrict__ cbh,
    const float* __restrict__ hc, int* __restrict__ out,
    int* __restrict__ list, int* __restrict__ count) {
  __shared__ unsigned short Alds[16384];  // 32 KB: 64 rows x 256 fp16 (swizzled)
  __shared__ unsigned short Blds[16384];  // 32 KB: 2 x (256 codes x 32 dims)
  __shared__ float c2s[1024];             // 4 KB
  __shared__ float cbv[4][64];            // cross-wave merge: best
  __shared__ int   cbi[4][64];            //   index
  __shared__ float csv[4][64];            //   second-best

  const int tid = threadIdx.x;
  const int lane = tid & 63;
  const int wave = tid >> 6;
  const int wr = wave >> 2;   // 0..1 (M)
  const int wc = wave & 3;    // 0..3 (N)
  const int l15 = lane & 15;
  const int l4  = lane >> 4;  // 0..3
  // XCD-aware swizzle: 512 blocks, 8 XCDs -> contiguous 64-block chunks per XCD
  const int bswz = (blockIdx.x & 7) * 64 + (blockIdx.x >> 3);
  const int r0 = bswz * 64;

  reinterpret_cast<float2*>(c2s)[tid] = reinterpret_cast<const float2*>(hc)[tid];

  // ---- Phase 0: A rows fp32 -> fp16 -> A_lds (once per block) ----
  {
    const int row = tid >> 3;          // 0..63
    const int cc  = tid & 7;           // col chunk (32 dims)
    const float* src = x + (size_t)(r0 + row) * 256 + cc * 32;
    unsigned short hv[32];
#pragma unroll
    for (int q = 0; q < 8; ++q) {
      float4 v = *reinterpret_cast<const float4*>(src + q * 4);
      hv[q * 4 + 0] = f2h(v.x); hv[q * 4 + 1] = f2h(v.y);
      hv[q * 4 + 2] = f2h(v.z); hv[q * 4 + 3] = f2h(v.w);
    }
    char* base = reinterpret_cast<char*>(Alds);
#pragma unroll
    for (int g = 0; g < 4; ++g) {
      int byte = (row * 512 + cc * 64 + g * 16) ^ ((row & 7) << 4);
      *reinterpret_cast<f16x8*>(base + byte) = *reinterpret_cast<const f16x8*>(&hv[g * 8]);
    }
  }

  // B staging: dest linear 16B granules; source chunk pre-swizzled by (code>>1)&3.
  auto stage = [&](int T1) {
    const int p = T1 & 1;
    const int n0 = (T1 >> 3) << 8;
    const int d0 = (T1 & 7) << 5;
    unsigned short* B = Blds + p * 8192;
#pragma unroll
    for (int r = 0; r < 2; ++r) {
      int idx = r * 512 + tid;
      int bch = (idx & 3) ^ ((idx >> 3) & 3);
      glds16(cbh + (size_t)(n0 + (idx >> 2)) * 256 + d0 + bch * 8, B + idx * 8);
    }
  };

  float bestv[2][4], secondv[2][4];
  int besti[2][4];
#pragma unroll
  for (int tr = 0; tr < 2; ++tr)
#pragma unroll
    for (int g = 0; g < 4; ++g) {
      bestv[tr][g] = -3.4e38f; secondv[tr][g] = -3.4e38f; besti[tr][g] = 0;
    }

  __syncthreads();   // A_lds complete
  stage(0);          // prologue: 2 glds in flight

  const int swzf = (l15 >> 1) & 3;  // B read-side chunk XOR ((code>>1)&3)
  // A fragment base byte addresses (per tr), swizzle folded in; dt/l4 offsets added in-loop
  int abase[2];
#pragma unroll
  for (int tr = 0; tr < 2; ++tr) {
    int arow = wr * 32 + tr * 16 + l15;
    abase[tr] = (arow * 512 + l4 * 16) ^ ((arow & 7) << 4);
  }

  int T = 0;
  for (int nt = 0; nt < 4; ++nt) {
    f32x4 acc[2][4];
#pragma unroll
    for (int tr = 0; tr < 2; ++tr)
#pragma unroll
      for (int tc = 0; tc < 4; ++tc) acc[tr][tc] = (f32x4){0.f, 0.f, 0.f, 0.f};

    for (int dt = 0; dt < 8; ++dt, ++T) {
      const int p = T & 1;
      if (T < 31) {
        stage(T + 1);
        // 2 newest (next stage) stay in flight; stage T's 2 are complete.
        asm volatile("s_waitcnt vmcnt(2)" ::: "memory");
      } else {
        asm volatile("s_waitcnt vmcnt(0)" ::: "memory");
      }
      __builtin_amdgcn_s_barrier();

      const char* Ab = reinterpret_cast<const char*>(Alds);
      const unsigned short* B = Blds + p * 8192;

      f16x8 af[2], bf[4];
#pragma unroll
      for (int tr = 0; tr < 2; ++tr)
        af[tr] = *reinterpret_cast<const f16x8*>(Ab + (abase[tr] ^ (dt * 64)));
#pragma unroll
      for (int tc = 0; tc < 4; ++tc) {
        int bcol = wc * 64 + tc * 16 + l15;
        bf[tc] = *reinterpret_cast<const f16x8*>(B + bcol * 32 + (l4 ^ swzf) * 8);
      }

#pragma unroll
      for (int tr = 0; tr < 2; ++tr)
#pragma unroll
        for (int tc = 0; tc < 4; ++tc)
          acc[tr][tc] = __builtin_amdgcn_mfma_f32_16x16x32_f16(af[tr], bf[tc], acc[tr][tc], 0, 0, 0);

      asm volatile("s_waitcnt lgkmcnt(0)" ::: "memory");
      __builtin_amdgcn_s_barrier();
    }

    // fold chunk scores into running best/second (codes ascending per thread)
    const int cb0 = nt * 256 + wc * 64 + l15;
    float hcv[4];
#pragma unroll
    for (int tc = 0; tc < 4; ++tc) hcv[tc] = c2s[cb0 + tc * 16];
#pragma unroll
    for (int tr = 0; tr < 2; ++tr)
#pragma unroll
      for (int tc = 0; tc < 4; ++tc) {
        const int code = cb0 + tc * 16;
#pragma unroll
        for (int g = 0; g < 4; ++g) {
          float s = acc[tr][tc][g] - hcv[tc];
          bool gt = s > bestv[tr][g];
          float ns = gt ? bestv[tr][g] : fmaxf(secondv[tr][g], s);
          bestv[tr][g] = gt ? s : bestv[tr][g];
          besti[tr][g] = gt ? code : besti[tr][g];
          secondv[tr][g] = ns;
        }
      }
  }

  // within-wave merge across the 16 l15-lanes sharing each row-slot
#pragma unroll
  for (int tr = 0; tr < 2; ++tr)
#pragma unroll
    for (int g = 0; g < 4; ++g) {
      float bv = bestv[tr][g]; int bi = besti[tr][g]; float sv = secondv[tr][g];
#pragma unroll
      for (int m = 1; m < 16; m <<= 1) {
        float ov = __shfl_xor(bv, m, 64);
        int   oi = __shfl_xor(bi, m, 64);
        float os = __shfl_xor(sv, m, 64);
        sv = fmaxf(fmaxf(sv, os), fminf(bv, ov));
        bool gt = (ov > bv) || (ov == bv && oi < bi);
        bv = gt ? ov : bv;
        bi = gt ? oi : bi;
      }
      if (l15 == 0) {
        int rl = wr * 32 + tr * 16 + l4 * 4 + g;
        cbv[wc][rl] = bv; cbi[wc][rl] = bi; csv[wc][rl] = sv;
      }
    }

  // cross-wave merge: each of 4 wc-waves surveyed a disjoint 64-code slice per chunk
  __syncthreads();
  if (tid < 64) {
    float bv = cbv[0][tid]; int bi = cbi[0][tid]; float sv = csv[0][tid];
#pragma unroll
    for (int w2 = 1; w2 < 4; ++w2) {
      float ov = cbv[w2][tid]; int oi = cbi[w2][tid]; float os = csv[w2][tid];
      sv = fmaxf(fmaxf(sv, os), fminf(bv, ov));
      bool gt = (ov > bv) || (ov == bv && oi < bi);
      bv = gt ? ov : bv;
      bi = gt ? oi : bi;
    }
    out[r0 + tid] = bi;
    if (sv >= bv - MARG) {           // ambiguous: append to compact recheck list
      int slot = atomicAdd(count, 1);
      list[slot] = r0 + tid;
    }
  }
}

// -------- cleanup v4 (unchanged): exact fp32 recompute, 4 rows/unit ---------------
__global__ __launch_bounds__(512) void vq_cleanup(const float* __restrict__ x,
                                                  const float* __restrict__ cb,
                                                  const float* __restrict__ hc,
                                                  const int* __restrict__ list,
                                                  const int* __restrict__ count,
                                                  int* __restrict__ out) {
  __shared__ float xt[4][256];    // 4 KB
  __shared__ int rowids[4];
  __shared__ float wbv[8][4];
  __shared__ int   wbi[8][4];
  const int tid = threadIdx.x;
  const int wave = tid >> 6;
  const int n = *count;

  for (int t0 = blockIdx.x * 4; t0 < n; t0 += gridDim.x * 4) {
    __syncthreads();  // protect LDS reuse across grid-stride iterations
    if (tid < 4) rowids[tid] = (t0 + tid < n) ? list[t0 + tid] : -1;
    __syncthreads();
    {
      int j = tid >> 7, seg = tid & 127;
      int row = rowids[j];
      if (row < 0) row = rowids[0];  // dead slot: stage any valid row (result unused)
      *reinterpret_cast<float2*>(&xt[j][seg * 2]) =
          *reinterpret_cast<const float2*>(x + (size_t)row * 256 + seg * 2);
    }
    __syncthreads();

    float acc0[4], acc1[4];
#pragma unroll
    for (int j = 0; j < 4; ++j) { acc0[j] = 0.f; acc1[j] = 0.f; }

    const float* c0 = cb + (size_t)tid * 256;
    const float* c1 = cb + (size_t)(512 + tid) * 256;
#pragma unroll 4
    for (int d0 = 0; d0 < 256; d0 += 4) {
      float4 ca = *reinterpret_cast<const float4*>(c0 + d0);
      float4 cd = *reinterpret_cast<const float4*>(c1 + d0);
#pragma unroll
      for (int j = 0; j < 4; ++j) {
        float4 xv = *reinterpret_cast<const float4*>(&xt[j][d0]);  // wave-broadcast
        acc0[j] = fmaf(ca.x, xv.x, acc0[j]);
        acc0[j] = fmaf(ca.y, xv.y, acc0[j]);
        acc0[j] = fmaf(ca.z, xv.z, acc0[j]);
        acc0[j] = fmaf(ca.w, xv.w, acc0[j]);
        acc1[j] = fmaf(cd.x, xv.x, acc1[j]);
        acc1[j] = fmaf(cd.y, xv.y, acc1[j]);
        acc1[j] = fmaf(cd.z, xv.z, acc1[j]);
        acc1[j] = fmaf(cd.w, xv.w, acc1[j]);
      }
    }

    const float h0 = hc[tid];
    const float h1 = hc[512 + tid];

#pragma unroll
    for (int j = 0; j < 4; ++j) {
      float bv = acc0[j] - h0; int bi = tid;
      float s1 = acc1[j] - h1;
      if (s1 > bv) { bv = s1; bi = 512 + tid; }  // codes ascending -> strict >
#pragma unroll
      for (int m = 1; m < 64; m <<= 1) {
        float ov = __shfl_xor(bv, m, 64);
        int   oi = __shfl_xor(bi, m, 64);
        bool gt = (ov > bv) || (ov == bv && oi < bi);
        bv = gt ? ov : bv;
        bi = gt ? oi : bi;
      }
      if ((tid & 63) == 0) { wbv[wave][j] = bv; wbi[wave][j] = bi; }
    }
    __syncthreads();
    if (tid < 4 && rowids[tid] >= 0) {
      float bv = wbv[0][tid]; int bi = wbi[0][tid];
#pragma unroll
      for (int w2 = 1; w2 < 8; ++w2) {
        float ov = wbv[w2][tid]; int oi = wbi[w2][tid];
        if (ov > bv || (ov == bv && oi < bi)) { bv = ov; bi = oi; }
      }
      out[rowids[tid]] = bi;
    }
  }
}

// ================= fallback fp32 path (R2 kernel) if ws is too small =================
#define BM 128
#define BN 256
#define BD 32
#define NT 512

__global__ __launch_bounds__(256) void vq_c2_kernel(const float* __restrict__ cb,
                                                    float* __restrict__ halfc2) {
  int row  = blockIdx.x * 4 + (threadIdx.x >> 6);
  int lane = threadIdx.x & 63;
  float4 v = *reinterpret_cast<const float4*>(cb + (size_t)row * 256 + lane * 4);
  float s = v.x * v.x + v.y * v.y + v.z * v.z + v.w * v.w;
#pragma unroll
  for (int m = 32; m >= 1; m >>= 1) s += __shfl_xor(s, m, 64);
  if (lane == 0) halfc2[row] = 0.5f * s;
}

__global__ __launch_bounds__(NT, 2) void vq_argmin_kernel(
    const float* __restrict__ x, const float* __restrict__ cb,
    const float* __restrict__ halfc2, int* __restrict__ out) {
  __shared__ float lds[2][(BM + BN) * BD];
  __shared__ float c2s[1024];
  const int tid = threadIdx.x;
  const int w   = tid >> 6;
  const int tc  = tid & 31;
  const int tr  = tid >> 5;
  const int r0  = blockIdx.x * BM;
  reinterpret_cast<float2*>(c2s)[tid] = reinterpret_cast<const float2*>(halfc2)[tid];
  const int sA  = tr & 7;
  const int sB  = tc & 7;
  const int sAB = sA ^ sB;
  const int cho = (((tid & 7) ^ w)) * 4;
  const int sub = tid >> 3;
  float bestv[8]; int besti[8];
#pragma unroll
  for (int i = 0; i < 8; ++i) { bestv[i] = -3.4e38f; besti[i] = 0; }
  auto stage = [&](int n0, int d0, int p) {
    float* dst  = &lds[p][0];
    float* dstB = dst + BM * BD;
#pragma unroll
    for (int r = 0; r < 2; ++r) {
      int t2 = r * NT + tid;
      glds16(x + (size_t)(r0 + r * 64 + sub) * 256 + d0 + cho, dst + t2 * 4);
    }
#pragma unroll
    for (int r = 0; r < 4; ++r) {
      int t2 = r * NT + tid;
      glds16(cb + (size_t)(n0 + r * 64 + sub) * 256 + d0 + cho, dstB + t2 * 4);
    }
  };
  stage(0, 0, 0);
  int t = 0;
  for (int nt = 0; nt < 4; ++nt) {
    float acc[8][8];
#pragma unroll
    for (int i = 0; i < 8; ++i)
#pragma unroll
      for (int j = 0; j < 8; ++j) acc[i][j] = 0.f;
    for (int dt = 0; dt < 8; ++dt, ++t) {
      const int p = t & 1;
      if (t < 31) {
        const int t1 = t + 1;
        stage((t1 >> 3) * BN, (t1 & 7) * BD, t1 & 1);
        asm volatile("s_waitcnt vmcnt(6)" ::: "memory");
      } else {
        asm volatile("s_waitcnt vmcnt(0)" ::: "memory");
      }
      __builtin_amdgcn_s_barrier();
      const float* pA = &lds[p][tr * 8 * BD];
      const float* pB = &lds[p][BM * BD + tc * 8 * BD];
#pragma unroll
      for (int cc = 0; cc < 8; ++cc) {
        const float* pBc = pB + ((cc ^ sAB) << 2);
        float4 a[8], b[8];
#pragma unroll
        for (int i = 0; i < 8; ++i)
          a[i] = *reinterpret_cast<const float4*>(pA + i * BD + cc * 4);
#pragma unroll
        for (int j = 0; j < 8; ++j)
          b[j] = *reinterpret_cast<const float4*>(pBc + j * BD);
#pragma unroll
        for (int i = 0; i < 8; ++i)
#pragma unroll
          for (int j = 0; j < 8; ++j) {
            acc[i][j] = fmaf(a[i].x, b[j].x, acc[i][j]);
            acc[i][j] = fmaf(a[i].y, b[j].y, acc[i][j]);
            acc[i][j] = fmaf(a[i].z, b[j].z, acc[i][j]);
            acc[i][j] = fmaf(a[i].w, b[j].w, acc[i][j]);
          }
      }
      asm volatile("s_waitcnt lgkmcnt(0)" ::: "memory");
      __builtin_amdgcn_s_barrier();
    }
    const int n0 = nt * BN;
#pragma unroll
    for (int j = 0; j < 8; ++j) {
      const int code = n0 + tc * 8 + j;
      const float hc = c2s[code];
#pragma unroll
      for (int i = 0; i < 8; ++i) {
        float s = acc[i][j] - hc;
        if (s > bestv[i]) { bestv[i] = s; besti[i] = code; }
      }
    }
  }
#pragma unroll
  for (int i = 0; i < 8; ++i) {
#pragma unroll
    for (int m = 1; m <= 16; m <<= 1) {
      float ov = __shfl_xor(bestv[i], m, 64);
      int   oi = __shfl_xor(besti[i], m, 64);
      if (ov > bestv[i] || (ov == bestv[i] && oi < besti[i])) { bestv[i] = ov; besti[i] = oi; }
    }
  }
  if (tc == 0) {
#pragma unroll
    for (int i = 0; i < 8; ++i) out[r0 + tr * 8 + i] = besti[i];
  }
}

// ==================================== launch ====================================
extern "C" void kernel_launch(void* const* d_in, const int* in_sizes, int n_in,
                              void* d_out, int out_size, void* d_ws, size_t ws_size,
                              hipStream_t stream) {
  const float* x  = (const float*)d_in[0];   // (8,4096,256) fp32
  const float* cb = (const float*)d_in[1];   // (1024,256) fp32
  int* out = (int*)d_out;                    // (8,4096) int32

  // ws layout (bytes): cbh 512K | hc 4K | list 128K | count 4
  const size_t OFF_CH = 0;
  const size_t OFF_HC = OFF_CH + (size_t)1024 * 256 * 2;
  const size_t OFF_LS = OFF_HC + (size_t)1024 * 4;
  const size_t OFF_CT = OFF_LS + (size_t)32768 * 4;
  const size_t NEED   = OFF_CT + 64;

  if (ws_size >= NEED) {
    unsigned short* cbh = (unsigned short*)((char*)d_ws + OFF_CH);
    float* hc  = (float*)((char*)d_ws + OFF_HC);
    int* list  = (int*)((char*)d_ws + OFF_LS);
    int* count = (int*)((char*)d_ws + OFF_CT);

    hipLaunchKernelGGL(vq_prep_cb, dim3(256), dim3(256), 0, stream, cb, cbh, hc, count);
    hipLaunchKernelGGL(vq_mfma_kernel, dim3(512), dim3(512), 0, stream,
                       x, cbh, hc, out, list, count);
    hipLaunchKernelGGL(vq_cleanup, dim3(512), dim3(512), 0, stream,
                       x, cb, hc, list, count, out);
  } else {
    float* c2 = (float*)d_ws;
    hipLaunchKernelGGL(vq_c2_kernel, dim3(256), dim3(256), 0, stream, cb, c2);
    hipLaunchKernelGGL(vq_argmin_kernel, dim3(32768 / BM), dim3(NT), 0, stream,
                       x, cb, c2, out);
  }
}